// Round 1
// baseline (1093.971 us; speedup 1.0000x reference)
//
#include <hip/hip_runtime.h>
#include <math.h>

#define R_ROWS 26588
#define S_TOT  13294
#define NHEAD  8
#define NLVL   4
#define EPSF   1e-5f

// ---------------------------------------------------------------------------
// q = a + b (elementwise)
// ---------------------------------------------------------------------------
__global__ __launch_bounds__(256) void add2_kernel(
    const float* __restrict__ a, const float* __restrict__ b,
    float* __restrict__ c, int n)
{
    int i = blockIdx.x * 256 + threadIdx.x;
    if (i < n) c[i] = a[i] + b[i];
}

// ---------------------------------------------------------------------------
// C[M,N] = A[M,K] @ W[K,N] + bias[N]   (optional ReLU)
// 64x64 block tile, 256 threads, 4x4 microtile, BK=16.
// N multiple of 64, K multiple of 16 (true for all calls); M has tail guard.
// ---------------------------------------------------------------------------
template<bool RELU>
__global__ __launch_bounds__(256) void gemm_bias_kernel(
    const float* __restrict__ A, const float* __restrict__ W,
    const float* __restrict__ bias, float* __restrict__ C,
    int M, int N, int K)
{
    __shared__ float As[16][68];   // [k][m], +4 pad keeps 16B align, breaks conflicts
    __shared__ float Bs[16][68];   // [k][n]

    const int tid = threadIdx.x;
    const int bm  = blockIdx.x * 64;
    const int bn  = blockIdx.y * 64;
    const int tx  = tid & 15;       // col group
    const int ty  = tid >> 4;       // row group

    const int a_k = tid & 15;       // A-load: k fast for coalescing
    const int a_m = tid >> 4;
    const int w_n = tid & 63;       // W-load: n fast for coalescing
    const int w_k = tid >> 6;

    float acc[4][4] = {};

    for (int k0 = 0; k0 < K; k0 += 16) {
#pragma unroll
        for (int i = 0; i < 4; ++i) {
            int m = bm + a_m + i * 16;
            As[a_k][a_m + i * 16] = (m < M) ? A[(long)m * K + k0 + a_k] : 0.f;
        }
#pragma unroll
        for (int i = 0; i < 4; ++i) {
            int k = w_k + i * 4;
            Bs[k][w_n] = W[(long)(k0 + k) * N + bn + w_n];
        }
        __syncthreads();
#pragma unroll
        for (int k = 0; k < 16; ++k) {
            float a[4], b[4];
#pragma unroll
            for (int i = 0; i < 4; ++i) a[i] = As[k][ty * 4 + i];
#pragma unroll
            for (int j = 0; j < 4; ++j) b[j] = Bs[k][tx * 4 + j];
#pragma unroll
            for (int i = 0; i < 4; ++i)
#pragma unroll
                for (int j = 0; j < 4; ++j) acc[i][j] += a[i] * b[j];
        }
        __syncthreads();
    }

#pragma unroll
    for (int i = 0; i < 4; ++i) {
        int m = bm + ty * 4 + i;
        if (m >= M) continue;
#pragma unroll
        for (int j = 0; j < 4; ++j) {
            int n = bn + tx * 4 + j;
            float v = acc[i][j] + bias[n];
            if (RELU) v = fmaxf(v, 0.f);
            C[(long)m * N + n] = v;
        }
    }
}

// ---------------------------------------------------------------------------
// softmax over groups of 16 contiguous floats (per (row, head)), in place
// ---------------------------------------------------------------------------
__global__ __launch_bounds__(256) void softmax16_kernel(float* __restrict__ aw, int total)
{
    int g = blockIdx.x * 256 + threadIdx.x;
    if (g >= total) return;
    float* p = aw + (long)g * 16;
    float v[16];
    float mx = -1e30f;
#pragma unroll
    for (int i = 0; i < 16; ++i) { v[i] = p[i]; mx = fmaxf(mx, v[i]); }
    float s = 0.f;
#pragma unroll
    for (int i = 0; i < 16; ++i) { v[i] = expf(v[i] - mx); s += v[i]; }
    float inv = 1.f / s;
#pragma unroll
    for (int i = 0; i < 16; ++i) p[i] = v[i] * inv;
}

// ---------------------------------------------------------------------------
// Deformable attention sampling.
// 32 lanes (channels) per (row, head) group; 8 groups per 256-thread block.
// v layout: (B, S, NH, HD) ; off: (R, NH*L*P*2) ; aw: (R, NH*16)
// out: (R, NH*HD) == (B, S, D)
// ---------------------------------------------------------------------------
__global__ __launch_bounds__(256) void deform_sample_kernel(
    const float* __restrict__ v, const float* __restrict__ off,
    const float* __restrict__ aw, const float* __restrict__ vr,
    float* __restrict__ out)
{
    const int Hs[4] = {100, 50, 25, 13};
    const int S0[4] = {0, 10000, 12500, 13125};

    int grp = blockIdx.x * 8 + (threadIdx.x >> 5);
    int hd  = threadIdx.x & 31;
    if (grp >= R_ROWS * NHEAD) return;
    int h = grp & 7;
    int r = grp >> 3;
    int b = (r >= S_TOT) ? 1 : 0;
    int s = r - b * S_TOT;

    // reference point from the query's own level
    int lq = (s < 10000) ? 0 : (s < 12500) ? 1 : (s < 13125) ? 2 : 3;
    int t  = s - S0[lq];
    int Wq = Hs[lq];                 // square levels: H == W
    int iy = t / Wq;
    int jx = t - iy * Wq;
    float vx = vr[(b * NLVL + lq) * 2 + 0];
    float vy = vr[(b * NLVL + lq) * 2 + 1];
    float rx = (jx + 0.5f) / (vx * (float)Wq);
    float ry = (iy + 0.5f) / (vy * (float)Hs[lq]);

    const float* offp = off + (long)r * 256 + h * 32;
    const float* awp  = aw + ((long)r * NHEAD + h) * 16;

    float acc = 0.f;
#pragma unroll
    for (int l = 0; l < 4; ++l) {
        const int H = Hs[l], W = Hs[l];
        const float fW = (float)W, fH = (float)H;
        const float* vbase = v + ((long)(b * S_TOT + S0[l])) * 256 + h * 32 + hd;
#pragma unroll
        for (int p = 0; p < 4; ++p) {
            float ox = offp[l * 8 + p * 2 + 0];
            float oy = offp[l * 8 + p * 2 + 1];
            float w  = awp[l * 4 + p];
            float locx = rx + ox / fW;
            float locy = ry + oy / fH;
            float x = locx * fW - 0.5f;
            float y = locy * fH - 0.5f;
            float xf = floorf(x), yf = floorf(y);
            float lx = x - xf, ly = y - yf;
            int x0 = (int)xf, y0 = (int)yf;
            float w00 = (1.f - lx) * (1.f - ly) * w;
            float w01 = lx * (1.f - ly) * w;
            float w10 = (1.f - lx) * ly * w;
            float w11 = lx * ly * w;
            bool xv0 = (x0 >= 0) && (x0 < W);
            bool xv1 = (x0 + 1 >= 0) && (x0 + 1 < W);
            bool yv0 = (y0 >= 0) && (y0 < H);
            bool yv1 = (y0 + 1 >= 0) && (y0 + 1 < H);
            if (yv0) {
                if (xv0) acc += vbase[(y0 * W + x0) * 256] * w00;
                if (xv1) acc += vbase[(y0 * W + x0 + 1) * 256] * w01;
            }
            if (yv1) {
                if (xv0) acc += vbase[((y0 + 1) * W + x0) * 256] * w10;
                if (xv1) acc += vbase[((y0 + 1) * W + x0 + 1) * 256] * w11;
            }
        }
    }
    out[(long)r * 256 + h * 32 + hd] = acc;
}

// ---------------------------------------------------------------------------
// out = LayerNorm(a + b) * g + beta, one 256-thread block per row (D=256)
// ---------------------------------------------------------------------------
__global__ __launch_bounds__(256) void add_ln_kernel(
    const float* __restrict__ a, const float* __restrict__ b,
    const float* __restrict__ g, const float* __restrict__ beta,
    float* __restrict__ out)
{
    int row = blockIdx.x;
    int tid = threadIdx.x;
    float x = a[(long)row * 256 + tid] + b[(long)row * 256 + tid];
    float s1 = x, s2 = x * x;
#pragma unroll
    for (int o = 32; o > 0; o >>= 1) {
        s1 += __shfl_down(s1, o, 64);
        s2 += __shfl_down(s2, o, 64);
    }
    __shared__ float sh1[4], sh2[4];
    int w = tid >> 6;
    if ((tid & 63) == 0) { sh1[w] = s1; sh2[w] = s2; }
    __syncthreads();
    float t1 = sh1[0] + sh1[1] + sh1[2] + sh1[3];
    float t2 = sh2[0] + sh2[1] + sh2[2] + sh2[3];
    float mean = t1 * (1.f / 256.f);
    float var  = t2 * (1.f / 256.f) - mean * mean;
    float inv  = rsqrtf(var + EPSF);
    out[(long)row * 256 + tid] = (x - mean) * inv * g[tid] + beta[tid];
}

// ---------------------------------------------------------------------------
extern "C" void kernel_launch(void* const* d_in, const int* in_sizes, int n_in,
                              void* d_out, int out_size, void* d_ws, size_t ws_size,
                              hipStream_t stream)
{
    const float* query  = (const float*)d_in[0];
    const float* qpos   = (const float*)d_in[1];
    const float* vr     = (const float*)d_in[2];
    // d_in[3] spatial_shapes (int64), d_in[4] level_start_index (int64): compile-time constants
    const float* W_off  = (const float*)d_in[5];
    const float* b_off  = (const float*)d_in[6];
    const float* W_attn = (const float*)d_in[7];
    const float* b_attn = (const float*)d_in[8];
    const float* W_val  = (const float*)d_in[9];
    const float* b_val  = (const float*)d_in[10];
    const float* W_out  = (const float*)d_in[11];
    const float* b_out  = (const float*)d_in[12];
    const float* ln1g   = (const float*)d_in[13];
    const float* ln1b   = (const float*)d_in[14];
    const float* W1     = (const float*)d_in[15];
    const float* b1     = (const float*)d_in[16];
    const float* W2     = (const float*)d_in[17];
    const float* b2     = (const float*)d_in[18];
    const float* ln2g   = (const float*)d_in[19];
    const float* ln2b   = (const float*)d_in[20];
    float* out = (float*)d_out;

    float* ws = (float*)d_ws;
    const long RC = (long)R_ROWS * 256;
    float* qb   = ws;                              // q = query+pos; later sampled attn
    float* vb   = ws + RC;                         // value proj; later LN1 output x
    float* cb   = ws + 2 * RC;                     // off; later attn_out; later f
    float* awb  = ws + 3 * RC;                     // attention weights (R x 128)
    float* ffb  = ws + 3 * RC + (long)R_ROWS * 128; // FF hidden (R x 1024)

    dim3 blk(256);
    dim3 g44((R_ROWS + 63) / 64, 4);
    dim3 g42((R_ROWS + 63) / 64, 2);
    dim3 g416((R_ROWS + 63) / 64, 16);

    // 1. q = query + query_pos
    add2_kernel<<<(R_ROWS * 256 + 255) / 256, blk, 0, stream>>>(query, qpos, qb, R_ROWS * 256);
    // 2. v = query @ W_val + b_val      (layout (B,S,NH,HD))
    gemm_bias_kernel<false><<<g44, blk, 0, stream>>>(query, W_val, b_val, vb, R_ROWS, 256, 256);
    // 3. off = q @ W_off + b_off
    gemm_bias_kernel<false><<<g44, blk, 0, stream>>>(qb, W_off, b_off, cb, R_ROWS, 256, 256);
    // 4. attn logits = q @ W_attn + b_attn
    gemm_bias_kernel<false><<<g42, blk, 0, stream>>>(qb, W_attn, b_attn, awb, R_ROWS, 128, 256);
    // 5. softmax over 16 per (row, head)
    softmax16_kernel<<<(R_ROWS * NHEAD + 255) / 256, blk, 0, stream>>>(awb, R_ROWS * NHEAD);
    // 6. deformable sampling -> qb (q no longer needed)
    deform_sample_kernel<<<(R_ROWS * NHEAD) / 8, blk, 0, stream>>>(vb, cb, awb, vr, qb);
    // 7. attn_out = sampled @ W_out + b_out -> cb
    gemm_bias_kernel<false><<<g44, blk, 0, stream>>>(qb, W_out, b_out, cb, R_ROWS, 256, 256);
    // 8. x = LN(query + attn_out) -> vb
    add_ln_kernel<<<R_ROWS, blk, 0, stream>>>(query, cb, ln1g, ln1b, vb);
    // 9. h = relu(x @ W1 + b1) -> ffb
    gemm_bias_kernel<true><<<g416, blk, 0, stream>>>(vb, W1, b1, ffb, R_ROWS, 1024, 256);
    // 10. f = h @ W2 + b2 -> cb
    gemm_bias_kernel<false><<<g44, blk, 0, stream>>>(ffb, W2, b2, cb, R_ROWS, 256, 1024);
    // 11. out = LN(x + f)
    add_ln_kernel<<<R_ROWS, blk, 0, stream>>>(vb, cb, ln2g, ln2b, out);
}

// Round 2
// 478.022 us; speedup vs baseline: 2.2885x; 2.2885x over previous
//
#include <hip/hip_runtime.h>
#include <math.h>

#define R_ROWS 26588
#define S_TOT  13294
#define NHEAD  8
#define NLVL   4
#define EPSF   1e-5f

typedef __attribute__((ext_vector_type(8))) short short8;
typedef __attribute__((ext_vector_type(4))) float f32x4;

__device__ __forceinline__ unsigned short f2bf(float f) {
    unsigned int u = __builtin_bit_cast(unsigned int, f);
    unsigned int r = (u + 0x7FFFu + ((u >> 16) & 1u)) >> 16;   // RNE
    return (unsigned short)r;
}

// ---------------------------------------------------------------------------
// Transpose + convert: src f32 [K][N] -> dst bf16 [N][K].  K,N multiples of 32.
// block 256 = 32x8, grid (N/32, K/32)
// ---------------------------------------------------------------------------
__global__ __launch_bounds__(256) void transpose_cvt_kernel(
    const float* __restrict__ src, unsigned short* __restrict__ dst, int K, int N)
{
    __shared__ unsigned short t[32][33];
    int bn = blockIdx.x * 32, bk = blockIdx.y * 32;
    int x = threadIdx.x & 31;
    int y = threadIdx.x >> 5;
#pragma unroll
    for (int i = 0; i < 4; ++i) {
        int k = y + i * 8;
        t[x][k] = f2bf(src[(long)(bk + k) * N + bn + x]);
    }
    __syncthreads();
#pragma unroll
    for (int i = 0; i < 4; ++i) {
        int n = y + i * 8;
        dst[(long)(bn + n) * K + bk + x] = t[n][x];
    }
}

// ---------------------------------------------------------------------------
// MFMA GEMM: C[M,N] = A[M,K] (+A2) @ W + bias, W given pre-transposed bf16 [N][K].
// Block 256 (4 waves), tile 128(M) x 64(N), BK=32. Wave computes 32x64.
// A_BF16: A is bf16 [M][K]; else f32 (optionally fused A+A2).
// OUT_BF16: C stored bf16; RELU optional.
// ---------------------------------------------------------------------------
template<bool A_BF16, bool OUT_BF16, bool RELU, bool ADD2>
__global__ __launch_bounds__(256) void gemm_mfma_kernel(
    const void* __restrict__ Av, const float* __restrict__ A2,
    const unsigned short* __restrict__ Wt, const float* __restrict__ bias,
    void* __restrict__ Cv, int M, int N, int K)
{
    __shared__ unsigned short As[128][40];   // [m][k], pad to 40 (80B rows, 16B aligned)
    __shared__ unsigned short Bs[64][40];    // [n][k]

    const int tid  = threadIdx.x;
    const int bm   = blockIdx.x * 128;
    const int bn   = blockIdx.y * 64;
    const int wave = tid >> 6;
    const int lane = tid & 63;
    const int l15  = lane & 15;
    const int quad = lane >> 4;

    f32x4 acc[2][4];
#pragma unroll
    for (int i = 0; i < 2; ++i)
#pragma unroll
        for (int j = 0; j < 4; ++j) acc[i][j] = (f32x4)0.0f;

    for (int k0 = 0; k0 < K; k0 += 32) {
        // ---- stage A tile (128 x 32) ----
        if (A_BF16) {
            const unsigned short* A = (const unsigned short*)Av;
            int kq = (tid & 3) * 8;
            int r0 = tid >> 2;                       // 0..63
#pragma unroll
            for (int i = 0; i < 2; ++i) {
                int r = r0 + i * 64;
                int m = bm + r;
                uint4 val;
                val.x = val.y = val.z = val.w = 0u;
                if (m < M) val = *(const uint4*)&A[(long)m * K + k0 + kq];
                *(uint4*)&As[r][kq] = val;
            }
        } else {
            const float* A = (const float*)Av;
            int kq = (tid & 7) * 4;
            int r0 = tid >> 3;                       // 0..31
#pragma unroll
            for (int i = 0; i < 4; ++i) {
                int r = r0 + i * 32;
                int m = bm + r;
                float4 av;
                av.x = av.y = av.z = av.w = 0.f;
                if (m < M) {
                    av = *(const float4*)&A[(long)m * K + k0 + kq];
                    if (ADD2) {
                        float4 bv = *(const float4*)&A2[(long)m * K + k0 + kq];
                        av.x += bv.x; av.y += bv.y; av.z += bv.z; av.w += bv.w;
                    }
                }
                uint2 p;
                p.x = (unsigned)f2bf(av.x) | ((unsigned)f2bf(av.y) << 16);
                p.y = (unsigned)f2bf(av.z) | ((unsigned)f2bf(av.w) << 16);
                *(uint2*)&As[r][kq] = p;
            }
        }
        // ---- stage B tile (64 n x 32 k) from Wt[N][K] ----
        {
            int kq = (tid & 3) * 8;
            int n  = tid >> 2;                       // 0..63
            *(uint4*)&Bs[n][kq] = *(const uint4*)&Wt[(long)(bn + n) * K + k0 + kq];
        }
        __syncthreads();

        short8 af[2], bf[4];
#pragma unroll
        for (int mi = 0; mi < 2; ++mi)
            af[mi] = *(const short8*)&As[wave * 32 + mi * 16 + l15][quad * 8];
#pragma unroll
        for (int ni = 0; ni < 4; ++ni)
            bf[ni] = *(const short8*)&Bs[ni * 16 + l15][quad * 8];
#pragma unroll
        for (int mi = 0; mi < 2; ++mi)
#pragma unroll
            for (int ni = 0; ni < 4; ++ni)
                acc[mi][ni] = __builtin_amdgcn_mfma_f32_16x16x32_bf16(
                    af[mi], bf[ni], acc[mi][ni], 0, 0, 0);
        __syncthreads();
    }

    // ---- epilogue ----
#pragma unroll
    for (int mi = 0; mi < 2; ++mi) {
#pragma unroll
        for (int r = 0; r < 4; ++r) {
            int row = bm + wave * 32 + mi * 16 + quad * 4 + r;
            if (row >= M) continue;
#pragma unroll
            for (int ni = 0; ni < 4; ++ni) {
                int col = bn + ni * 16 + l15;
                float vv = acc[mi][ni][r] + bias[col];
                if (RELU) vv = fmaxf(vv, 0.f);
                if (OUT_BF16)
                    ((unsigned short*)Cv)[(long)row * N + col] = f2bf(vv);
                else
                    ((float*)Cv)[(long)row * N + col] = vv;
            }
        }
    }
}

// ---------------------------------------------------------------------------
// softmax over groups of 16 contiguous floats (per (row, head)), in place
// ---------------------------------------------------------------------------
__global__ __launch_bounds__(256) void softmax16_kernel(float* __restrict__ aw, int total)
{
    int g = blockIdx.x * 256 + threadIdx.x;
    if (g >= total) return;
    float* p = aw + (long)g * 16;
    float v[16];
    float mx = -1e30f;
#pragma unroll
    for (int i = 0; i < 16; ++i) { v[i] = p[i]; mx = fmaxf(mx, v[i]); }
    float s = 0.f;
#pragma unroll
    for (int i = 0; i < 16; ++i) { v[i] = expf(v[i] - mx); s += v[i]; }
    float inv = 1.f / s;
#pragma unroll
    for (int i = 0; i < 16; ++i) p[i] = v[i] * inv;
}

// ---------------------------------------------------------------------------
// Deformable attention sampling. 8 lanes per (row,head) group, 4 channels/lane
// (float4). 32 groups per 256-thread block.
// v: (B,S,NH,HD) f32 ; off: (R, NH*L*P*2) ; aw: (R, NH*16) ; out: (R, 256)
// ---------------------------------------------------------------------------
__global__ __launch_bounds__(256) void deform_sample_kernel(
    const float* __restrict__ v, const float* __restrict__ off,
    const float* __restrict__ aw, const float* __restrict__ vr,
    float* __restrict__ out)
{
    const int Hs[4] = {100, 50, 25, 13};
    const int S0[4] = {0, 10000, 12500, 13125};

    int grp = blockIdx.x * 32 + (threadIdx.x >> 3);
    int c4  = (threadIdx.x & 7) * 4;
    if (grp >= R_ROWS * NHEAD) return;
    int h = grp & 7;
    int r = grp >> 3;
    int b = (r >= S_TOT) ? 1 : 0;
    int s = r - b * S_TOT;

    int lq = (s < 10000) ? 0 : (s < 12500) ? 1 : (s < 13125) ? 2 : 3;
    int t  = s - S0[lq];
    int Wq = Hs[lq];
    int iy = t / Wq;
    int jx = t - iy * Wq;
    float vx = vr[(b * NLVL + lq) * 2 + 0];
    float vy = vr[(b * NLVL + lq) * 2 + 1];
    float rx = (jx + 0.5f) / (vx * (float)Wq);
    float ry = (iy + 0.5f) / (vy * (float)Hs[lq]);

    const float* offp = off + (long)r * 256 + h * 32;
    const float* awp  = aw + ((long)r * NHEAD + h) * 16;

    float ax = 0.f, ay = 0.f, az = 0.f, aw4 = 0.f;
#pragma unroll
    for (int l = 0; l < 4; ++l) {
        const int H = Hs[l], W = Hs[l];
        const float fW = (float)W, fH = (float)H;
        const float* vbase = v + ((long)(b * S_TOT + S0[l])) * 256 + h * 32 + c4;
#pragma unroll
        for (int p = 0; p < 4; ++p) {
            float ox = offp[l * 8 + p * 2 + 0];
            float oy = offp[l * 8 + p * 2 + 1];
            float w  = awp[l * 4 + p];
            float x = (rx + ox / fW) * fW - 0.5f;
            float y = (ry + oy / fH) * fH - 0.5f;
            float xf = floorf(x), yf = floorf(y);
            float lx = x - xf, ly = y - yf;
            int x0 = (int)xf, y0 = (int)yf;
            float w00 = (1.f - lx) * (1.f - ly) * w;
            float w01 = lx * (1.f - ly) * w;
            float w10 = (1.f - lx) * ly * w;
            float w11 = lx * ly * w;
            bool xv0 = (x0 >= 0) && (x0 < W);
            bool xv1 = (x0 + 1 >= 0) && (x0 + 1 < W);
            bool yv0 = (y0 >= 0) && (y0 < H);
            bool yv1 = (y0 + 1 >= 0) && (y0 + 1 < H);
            if (yv0) {
                if (xv0) {
                    float4 g = *(const float4*)&vbase[(long)(y0 * W + x0) * 256];
                    ax += g.x * w00; ay += g.y * w00; az += g.z * w00; aw4 += g.w * w00;
                }
                if (xv1) {
                    float4 g = *(const float4*)&vbase[(long)(y0 * W + x0 + 1) * 256];
                    ax += g.x * w01; ay += g.y * w01; az += g.z * w01; aw4 += g.w * w01;
                }
            }
            if (yv1) {
                if (xv0) {
                    float4 g = *(const float4*)&vbase[(long)((y0 + 1) * W + x0) * 256];
                    ax += g.x * w10; ay += g.y * w10; az += g.z * w10; aw4 += g.w * w10;
                }
                if (xv1) {
                    float4 g = *(const float4*)&vbase[(long)((y0 + 1) * W + x0 + 1) * 256];
                    ax += g.x * w11; ay += g.y * w11; az += g.z * w11; aw4 += g.w * w11;
                }
            }
        }
    }
    float4 o;
    o.x = ax; o.y = ay; o.z = az; o.w = aw4;
    *(float4*)&out[(long)r * 256 + h * 32 + c4] = o;
}

// ---------------------------------------------------------------------------
// out = LayerNorm(a + b) * g + beta, one 256-thread block per row (D=256)
// ---------------------------------------------------------------------------
__global__ __launch_bounds__(256) void add_ln_kernel(
    const float* __restrict__ a, const float* __restrict__ b,
    const float* __restrict__ g, const float* __restrict__ beta,
    float* __restrict__ out)
{
    int row = blockIdx.x;
    int tid = threadIdx.x;
    float x = a[(long)row * 256 + tid] + b[(long)row * 256 + tid];
    float s1 = x, s2 = x * x;
#pragma unroll
    for (int o = 32; o > 0; o >>= 1) {
        s1 += __shfl_down(s1, o, 64);
        s2 += __shfl_down(s2, o, 64);
    }
    __shared__ float sh1[4], sh2[4];
    int w = tid >> 6;
    if ((tid & 63) == 0) { sh1[w] = s1; sh2[w] = s2; }
    __syncthreads();
    float t1 = sh1[0] + sh1[1] + sh1[2] + sh1[3];
    float t2 = sh2[0] + sh2[1] + sh2[2] + sh2[3];
    float mean = t1 * (1.f / 256.f);
    float var  = t2 * (1.f / 256.f) - mean * mean;
    float inv  = rsqrtf(var + EPSF);
    out[(long)row * 256 + tid] = (x - mean) * inv * g[tid] + beta[tid];
}

// ---------------------------------------------------------------------------
extern "C" void kernel_launch(void* const* d_in, const int* in_sizes, int n_in,
                              void* d_out, int out_size, void* d_ws, size_t ws_size,
                              hipStream_t stream)
{
    const float* query  = (const float*)d_in[0];
    const float* qpos   = (const float*)d_in[1];
    const float* vr     = (const float*)d_in[2];
    const float* W_off  = (const float*)d_in[5];
    const float* b_off  = (const float*)d_in[6];
    const float* W_attn = (const float*)d_in[7];
    const float* b_attn = (const float*)d_in[8];
    const float* W_val  = (const float*)d_in[9];
    const float* b_val  = (const float*)d_in[10];
    const float* W_out  = (const float*)d_in[11];
    const float* b_out  = (const float*)d_in[12];
    const float* ln1g   = (const float*)d_in[13];
    const float* ln1b   = (const float*)d_in[14];
    const float* W1     = (const float*)d_in[15];
    const float* b1     = (const float*)d_in[16];
    const float* W2     = (const float*)d_in[17];
    const float* b2     = (const float*)d_in[18];
    const float* ln2g   = (const float*)d_in[19];
    const float* ln2b   = (const float*)d_in[20];
    float* out = (float*)d_out;

    float* ws = (float*)d_ws;
    const long RC = (long)R_ROWS * 256;
    float* qb  = ws;                                   // sampled attn out
    float* vb  = ws + RC;                              // value proj; later x (LN1)
    float* cb  = ws + 2 * RC;                          // off -> attn_out -> f
    float* awb = ws + 3 * RC;                          // attn weights (R x 128)
    unsigned short* ffb = (unsigned short*)(ws + 3 * RC + (long)R_ROWS * 128); // FF hidden bf16 (R x 1024)
    unsigned short* wt  = (unsigned short*)(ws + 3 * RC + (long)R_ROWS * 128 + (long)R_ROWS * 512);
    unsigned short* wt_val  = wt;                 // 256x256
    unsigned short* wt_off  = wt + 65536;         // 256x256
    unsigned short* wt_attn = wt + 131072;        // 128x256
    unsigned short* wt_out  = wt + 163840;        // 256x256
    unsigned short* wt_w1   = wt + 229376;        // 1024x256
    unsigned short* wt_w2   = wt + 491520;        // 256x1024

    dim3 blk(256);
    const int MB = (R_ROWS + 127) / 128;   // 208

    // 0. weight transpose + bf16 convert
    transpose_cvt_kernel<<<dim3(8, 8),  blk, 0, stream>>>(W_val,  wt_val,  256, 256);
    transpose_cvt_kernel<<<dim3(8, 8),  blk, 0, stream>>>(W_off,  wt_off,  256, 256);
    transpose_cvt_kernel<<<dim3(4, 8),  blk, 0, stream>>>(W_attn, wt_attn, 256, 128);
    transpose_cvt_kernel<<<dim3(8, 8),  blk, 0, stream>>>(W_out,  wt_out,  256, 256);
    transpose_cvt_kernel<<<dim3(32, 8), blk, 0, stream>>>(W1,     wt_w1,   256, 1024);
    transpose_cvt_kernel<<<dim3(8, 32), blk, 0, stream>>>(W2,     wt_w2,   1024, 256);

    // 1. v = query @ W_val + b_val -> vb
    gemm_mfma_kernel<false, false, false, false><<<dim3(MB, 4), blk, 0, stream>>>(
        query, nullptr, wt_val, b_val, vb, R_ROWS, 256, 256);
    // 2. off = (query+qpos) @ W_off + b_off -> cb
    gemm_mfma_kernel<false, false, false, true><<<dim3(MB, 4), blk, 0, stream>>>(
        query, qpos, wt_off, b_off, cb, R_ROWS, 256, 256);
    // 3. attn logits = (query+qpos) @ W_attn + b_attn -> awb
    gemm_mfma_kernel<false, false, false, true><<<dim3(MB, 2), blk, 0, stream>>>(
        query, qpos, wt_attn, b_attn, awb, R_ROWS, 128, 256);
    // 4. softmax over 16
    softmax16_kernel<<<(R_ROWS * NHEAD + 255) / 256, blk, 0, stream>>>(awb, R_ROWS * NHEAD);
    // 5. deformable sampling -> qb
    deform_sample_kernel<<<(R_ROWS * NHEAD) / 32, blk, 0, stream>>>(vb, cb, awb, vr, qb);
    // 6. attn_out = sampled @ W_out + b_out -> cb
    gemm_mfma_kernel<false, false, false, false><<<dim3(MB, 4), blk, 0, stream>>>(
        qb, nullptr, wt_out, b_out, cb, R_ROWS, 256, 256);
    // 7. x = LN(query + attn_out) -> vb
    add_ln_kernel<<<R_ROWS, blk, 0, stream>>>(query, cb, ln1g, ln1b, vb);
    // 8. h = relu(x @ W1 + b1) -> ffb (bf16)
    gemm_mfma_kernel<false, true, true, false><<<dim3(MB, 16), blk, 0, stream>>>(
        vb, nullptr, wt_w1, b1, ffb, R_ROWS, 1024, 256);
    // 9. f = h @ W2 + b2 -> cb
    gemm_mfma_kernel<true, false, false, false><<<dim3(MB, 4), blk, 0, stream>>>(
        ffb, nullptr, wt_w2, b2, cb, R_ROWS, 256, 1024);
    // 10. out = LN(x + f)
    add_ln_kernel<<<R_ROWS, blk, 0, stream>>>(vb, cb, ln2g, ln2b, out);
}

// Round 3
// 376.569 us; speedup vs baseline: 2.9051x; 1.2694x over previous
//
#include <hip/hip_runtime.h>
#include <math.h>

#define R_ROWS 26588
#define S_TOT  13294
#define NHEAD  8
#define NLVL   4
#define EPSF   1e-5f

typedef __attribute__((ext_vector_type(8))) short short8;
typedef __attribute__((ext_vector_type(4))) float f32x4;
typedef unsigned short ushort_t;

__device__ __forceinline__ unsigned short f2bf(float f) {
    unsigned int u = __builtin_bit_cast(unsigned int, f);
    unsigned int r = (u + 0x7FFFu + ((u >> 16) & 1u)) >> 16;   // RNE
    return (unsigned short)r;
}

// ---------------------------------------------------------------------------
// Transpose + convert: src f32 [K][N] -> dst bf16 [N][K].  K,N multiples of 32.
// ---------------------------------------------------------------------------
__global__ __launch_bounds__(256) void transpose_cvt_kernel(
    const float* __restrict__ src, ushort_t* __restrict__ dst, int K, int N)
{
    __shared__ ushort_t t[32][33];
    int bn = blockIdx.x * 32, bk = blockIdx.y * 32;
    int x = threadIdx.x & 31;
    int y = threadIdx.x >> 5;
#pragma unroll
    for (int i = 0; i < 4; ++i) {
        int k = y + i * 8;
        t[x][k] = f2bf(src[(long)(bk + k) * N + bn + x]);
    }
    __syncthreads();
#pragma unroll
    for (int i = 0; i < 4; ++i) {
        int n = y + i * 8;
        dst[(long)(bn + n) * K + bk + x] = t[n][x];
    }
}

// ---------------------------------------------------------------------------
// Elementwise: qry_bf = bf16(query), qsum_bf = bf16(query + qpos). 4 elem/thread.
// ---------------------------------------------------------------------------
__global__ __launch_bounds__(256) void addcvt_kernel(
    const float* __restrict__ q, const float* __restrict__ p,
    ushort_t* __restrict__ qry_bf, ushort_t* __restrict__ qsum_bf, int n4)
{
    int i = blockIdx.x * 256 + threadIdx.x;
    if (i >= n4) return;
    float4 a = ((const float4*)q)[i];
    float4 b = ((const float4*)p)[i];
    uint2 qa, qs;
    qa.x = (unsigned)f2bf(a.x) | ((unsigned)f2bf(a.y) << 16);
    qa.y = (unsigned)f2bf(a.z) | ((unsigned)f2bf(a.w) << 16);
    qs.x = (unsigned)f2bf(a.x + b.x) | ((unsigned)f2bf(a.y + b.y) << 16);
    qs.y = (unsigned)f2bf(a.z + b.z) | ((unsigned)f2bf(a.w + b.w) << 16);
    ((uint2*)qry_bf)[i] = qa;
    ((uint2*)qsum_bf)[i] = qs;
}

// ---------------------------------------------------------------------------
// MFMA GEMM: C[M,N] = A[M,K](bf16) @ W + bias.  Wt pre-transposed bf16 [N][K].
// Block 256 (4 waves), tile 128(M) x 128(N), BK=32. Wave: 32 rows x 128 cols.
// N multiple of 128, K multiple of 32. M tail-guarded.
// ---------------------------------------------------------------------------
template<bool OUT_BF16, bool RELU>
__global__ __launch_bounds__(256) void gemm_mfma_kernel(
    const ushort_t* __restrict__ A, const ushort_t* __restrict__ Wt,
    const float* __restrict__ bias, void* __restrict__ Cv,
    int M, int N, int K)
{
    __shared__ ushort_t As[128][40];   // [m][k], pad 32->40 breaks conflicts
    __shared__ ushort_t Bs[128][40];   // [n][k]

    const int tid  = threadIdx.x;
    const int bm   = blockIdx.x * 128;
    const int bn   = blockIdx.y * 128;
    const int wave = tid >> 6;
    const int lane = tid & 63;
    const int l15  = lane & 15;
    const int quad = lane >> 4;

    const int kq = (tid & 3) * 8;
    const int r0 = tid >> 2;          // 0..63

    f32x4 acc[2][8];
#pragma unroll
    for (int i = 0; i < 2; ++i)
#pragma unroll
        for (int j = 0; j < 8; ++j) acc[i][j] = (f32x4)0.0f;

    for (int k0 = 0; k0 < K; k0 += 32) {
#pragma unroll
        for (int i = 0; i < 2; ++i) {
            int r = r0 + i * 64;
            int m = bm + r;
            uint4 val; val.x = val.y = val.z = val.w = 0u;
            if (m < M) val = *(const uint4*)&A[(long)m * K + k0 + kq];
            *(uint4*)&As[r][kq] = val;
        }
#pragma unroll
        for (int i = 0; i < 2; ++i) {
            int n = r0 + i * 64;
            *(uint4*)&Bs[n][kq] = *(const uint4*)&Wt[(long)(bn + n) * K + k0 + kq];
        }
        __syncthreads();

        short8 af[2], bf[8];
#pragma unroll
        for (int mi = 0; mi < 2; ++mi)
            af[mi] = *(const short8*)&As[wave * 32 + mi * 16 + l15][quad * 8];
#pragma unroll
        for (int ni = 0; ni < 8; ++ni)
            bf[ni] = *(const short8*)&Bs[ni * 16 + l15][quad * 8];
#pragma unroll
        for (int mi = 0; mi < 2; ++mi)
#pragma unroll
            for (int ni = 0; ni < 8; ++ni)
                acc[mi][ni] = __builtin_amdgcn_mfma_f32_16x16x32_bf16(
                    af[mi], bf[ni], acc[mi][ni], 0, 0, 0);
        __syncthreads();
    }

#pragma unroll
    for (int mi = 0; mi < 2; ++mi) {
#pragma unroll
        for (int r = 0; r < 4; ++r) {
            int row = bm + wave * 32 + mi * 16 + quad * 4 + r;
            if (row >= M) continue;
#pragma unroll
            for (int ni = 0; ni < 8; ++ni) {
                int col = bn + ni * 16 + l15;
                float vv = acc[mi][ni][r] + bias[col];
                if (RELU) vv = fmaxf(vv, 0.f);
                if (OUT_BF16)
                    ((ushort_t*)Cv)[(long)row * N + col] = f2bf(vv);
                else
                    ((float*)Cv)[(long)row * N + col] = vv;
            }
        }
    }
}

// ---------------------------------------------------------------------------
// Deformable sampling + fused softmax.
// 4 lanes per (row,head) group, 8 bf16 channels/lane. 64 groups per block.
// v: (B,S,NH,HD) bf16 ; off: (R, NH*L*P*2) f32 ; logits: (R, NH*16) f32
// out: (R, 256) bf16
// ---------------------------------------------------------------------------
__global__ __launch_bounds__(256) void deform_sample_kernel(
    const ushort_t* __restrict__ v, const float* __restrict__ off,
    const float* __restrict__ logits, const float* __restrict__ vr,
    ushort_t* __restrict__ out)
{
    const int Hs[4] = {100, 50, 25, 13};
    const int S0[4] = {0, 10000, 12500, 13125};

    int grp = blockIdx.x * 64 + (threadIdx.x >> 2);
    int c8  = (threadIdx.x & 3) * 8;
    if (grp >= R_ROWS * NHEAD) return;
    int h = grp & 7;
    int r = grp >> 3;
    int b = (r >= S_TOT) ? 1 : 0;
    int s = r - b * S_TOT;

    int lq = (s < 10000) ? 0 : (s < 12500) ? 1 : (s < 13125) ? 2 : 3;
    int t  = s - S0[lq];
    int Wq = Hs[lq];
    int iy = t / Wq;
    int jx = t - iy * Wq;
    float vx = vr[(b * NLVL + lq) * 2 + 0];
    float vy = vr[(b * NLVL + lq) * 2 + 1];
    float rx = (jx + 0.5f) / (vx * (float)Wq);
    float ry = (iy + 0.5f) / (vy * (float)Hs[lq]);

    // fused softmax over the 16 logits of this (row, head)
    const float* lp = logits + (long)grp * 16;
    float w[16];
    {
        float4 l0 = *(const float4*)&lp[0];
        float4 l1 = *(const float4*)&lp[4];
        float4 l2 = *(const float4*)&lp[8];
        float4 l3 = *(const float4*)&lp[12];
        w[0]=l0.x; w[1]=l0.y; w[2]=l0.z; w[3]=l0.w;
        w[4]=l1.x; w[5]=l1.y; w[6]=l1.z; w[7]=l1.w;
        w[8]=l2.x; w[9]=l2.y; w[10]=l2.z; w[11]=l2.w;
        w[12]=l3.x; w[13]=l3.y; w[14]=l3.z; w[15]=l3.w;
        float mx = -1e30f;
#pragma unroll
        for (int i = 0; i < 16; ++i) mx = fmaxf(mx, w[i]);
        float sum = 0.f;
#pragma unroll
        for (int i = 0; i < 16; ++i) { w[i] = __expf(w[i] - mx); sum += w[i]; }
        float inv = 1.f / sum;
#pragma unroll
        for (int i = 0; i < 16; ++i) w[i] *= inv;
    }

    const float* offp = off + (long)r * 256 + h * 32;

    float acc[8];
#pragma unroll
    for (int i = 0; i < 8; ++i) acc[i] = 0.f;

#pragma unroll
    for (int l = 0; l < 4; ++l) {
        const int H = Hs[l], W = Hs[l];
        const float fW = (float)W, fH = (float)H;
        const ushort_t* vbase = v + ((long)(b * S_TOT + S0[l])) * 256 + h * 32 + c8;
#pragma unroll
        for (int p = 0; p < 4; ++p) {
            float ox = offp[l * 8 + p * 2 + 0];
            float oy = offp[l * 8 + p * 2 + 1];
            float ww = w[l * 4 + p];
            float x = (rx + ox / fW) * fW - 0.5f;
            float y = (ry + oy / fH) * fH - 0.5f;
            float xf = floorf(x), yf = floorf(y);
            float lx = x - xf, ly = y - yf;
            int x0 = (int)xf, y0 = (int)yf;
            float w00 = (1.f - lx) * (1.f - ly) * ww;
            float w01 = lx * (1.f - ly) * ww;
            float w10 = (1.f - lx) * ly * ww;
            float w11 = lx * ly * ww;
            bool xv0 = (x0 >= 0) && (x0 < W);
            bool xv1 = (x0 + 1 >= 0) && (x0 + 1 < W);
            bool yv0 = (y0 >= 0) && (y0 < H);
            bool yv1 = (y0 + 1 >= 0) && (y0 + 1 < H);
#define ACC_CORNER(IDX, WGT) do {                                          \
            uint4 g = *(const uint4*)&vbase[(long)(IDX) * 256];            \
            unsigned uu[4] = {g.x, g.y, g.z, g.w};                         \
            _Pragma("unroll")                                              \
            for (int ci = 0; ci < 4; ++ci) {                               \
                float lo = __builtin_bit_cast(float, uu[ci] << 16);        \
                float hi = __builtin_bit_cast(float, uu[ci] & 0xFFFF0000u);\
                acc[2*ci]   += lo * (WGT);                                 \
                acc[2*ci+1] += hi * (WGT);                                 \
            } } while (0)
            if (yv0) {
                if (xv0) ACC_CORNER(y0 * W + x0, w00);
                if (xv1) ACC_CORNER(y0 * W + x0 + 1, w01);
            }
            if (yv1) {
                if (xv0) ACC_CORNER((y0 + 1) * W + x0, w10);
                if (xv1) ACC_CORNER((y0 + 1) * W + x0 + 1, w11);
            }
#undef ACC_CORNER
        }
    }
    uint4 o;
    o.x = (unsigned)f2bf(acc[0]) | ((unsigned)f2bf(acc[1]) << 16);
    o.y = (unsigned)f2bf(acc[2]) | ((unsigned)f2bf(acc[3]) << 16);
    o.z = (unsigned)f2bf(acc[4]) | ((unsigned)f2bf(acc[5]) << 16);
    o.w = (unsigned)f2bf(acc[6]) | ((unsigned)f2bf(acc[7]) << 16);
    *(uint4*)&out[(long)r * 256 + h * 32 + c8] = o;
}

// ---------------------------------------------------------------------------
// out = LayerNorm(a + b); optionally also emit bf16 copy (for next GEMM's A)
// ---------------------------------------------------------------------------
template<bool DUAL>
__global__ __launch_bounds__(256) void add_ln_kernel(
    const float* __restrict__ a, const float* __restrict__ b,
    const float* __restrict__ g, const float* __restrict__ beta,
    float* __restrict__ outf, ushort_t* __restrict__ outb)
{
    int row = blockIdx.x;
    int tid = threadIdx.x;
    float x = a[(long)row * 256 + tid] + b[(long)row * 256 + tid];
    float s1 = x, s2 = x * x;
#pragma unroll
    for (int o = 32; o > 0; o >>= 1) {
        s1 += __shfl_down(s1, o, 64);
        s2 += __shfl_down(s2, o, 64);
    }
    __shared__ float sh1[4], sh2[4];
    int w = tid >> 6;
    if ((tid & 63) == 0) { sh1[w] = s1; sh2[w] = s2; }
    __syncthreads();
    float t1 = sh1[0] + sh1[1] + sh1[2] + sh1[3];
    float t2 = sh2[0] + sh2[1] + sh2[2] + sh2[3];
    float mean = t1 * (1.f / 256.f);
    float var  = t2 * (1.f / 256.f) - mean * mean;
    float inv  = rsqrtf(var + EPSF);
    float y = (x - mean) * inv * g[tid] + beta[tid];
    outf[(long)row * 256 + tid] = y;
    if (DUAL) outb[(long)row * 256 + tid] = f2bf(y);
}

// ---------------------------------------------------------------------------
extern "C" void kernel_launch(void* const* d_in, const int* in_sizes, int n_in,
                              void* d_out, int out_size, void* d_ws, size_t ws_size,
                              hipStream_t stream)
{
    const float* query  = (const float*)d_in[0];
    const float* qpos   = (const float*)d_in[1];
    const float* vr     = (const float*)d_in[2];
    const float* W_off  = (const float*)d_in[5];
    const float* b_off  = (const float*)d_in[6];
    const float* W_attn = (const float*)d_in[7];
    const float* b_attn = (const float*)d_in[8];
    const float* W_val  = (const float*)d_in[9];
    const float* b_val  = (const float*)d_in[10];
    const float* W_out  = (const float*)d_in[11];
    const float* b_out  = (const float*)d_in[12];
    const float* ln1g   = (const float*)d_in[13];
    const float* ln1b   = (const float*)d_in[14];
    const float* W1     = (const float*)d_in[15];
    const float* b1     = (const float*)d_in[16];
    const float* W2     = (const float*)d_in[17];
    const float* b2     = (const float*)d_in[18];
    const float* ln2g   = (const float*)d_in[19];
    const float* ln2b   = (const float*)d_in[20];
    float* out = (float*)d_out;

    float* ws = (float*)d_ws;
    const long R128 = (long)R_ROWS * 128;
    // bf16 buffers live in f32-slot units (2 shorts per slot)
    ushort_t* q_bf    = (ushort_t*)(ws);                 // R x 256 bf16  [dead after attn/off GEMM]
    ushort_t* qry_bf  = (ushort_t*)(ws + R128);          // R x 256 bf16  [dead after val GEMM]
    ushort_t* v_bf    = (ushort_t*)(ws + 2 * R128);      // R x 256 bf16  [dead after deform]
    float*    logits  = ws + 3 * R128;                   // R x 128 f32   [dead after deform]
    ushort_t* h_bf    = (ushort_t*)(ws);                 // R x 1024 bf16 overlays the 4 above (FF stage)
    float*    cb      = ws + 4 * R128;                   // R x 256 f32: off -> attn_out -> f
    ushort_t* samp_bf = (ushort_t*)(ws + 6 * R128);      // R x 256 bf16: sampled -> x_bf
    float*    xb      = ws + 7 * R128;                   // R x 256 f32: x (LN1 out)
    ushort_t* wt      = (ushort_t*)(ws + 9 * R128);      // weights bf16
    ushort_t* wt_val  = wt;                 // 256x256
    ushort_t* wt_off  = wt + 65536;         // 256x256
    ushort_t* wt_attn = wt + 131072;        // 128x256
    ushort_t* wt_out  = wt + 163840;        // 256x256
    ushort_t* wt_w1   = wt + 229376;        // 1024x256
    ushort_t* wt_w2   = wt + 491520;        // 256x1024

    dim3 blk(256);
    const int MB = (R_ROWS + 127) / 128;   // 208

    // 0. weight transpose + bf16 convert
    transpose_cvt_kernel<<<dim3(8, 8),  blk, 0, stream>>>(W_val,  wt_val,  256, 256);
    transpose_cvt_kernel<<<dim3(8, 8),  blk, 0, stream>>>(W_off,  wt_off,  256, 256);
    transpose_cvt_kernel<<<dim3(4, 8),  blk, 0, stream>>>(W_attn, wt_attn, 256, 128);
    transpose_cvt_kernel<<<dim3(8, 8),  blk, 0, stream>>>(W_out,  wt_out,  256, 256);
    transpose_cvt_kernel<<<dim3(32, 8), blk, 0, stream>>>(W1,     wt_w1,   256, 1024);
    transpose_cvt_kernel<<<dim3(8, 32), blk, 0, stream>>>(W2,     wt_w2,   1024, 256);

    // 1. qry_bf = bf16(query); q_bf = bf16(query + qpos)
    addcvt_kernel<<<(R_ROWS * 64 + 255) / 256, blk, 0, stream>>>(
        query, qpos, qry_bf, q_bf, R_ROWS * 64);
    // 2. v = query @ W_val + b_val -> v_bf (bf16)
    gemm_mfma_kernel<true, false><<<dim3(MB, 2), blk, 0, stream>>>(
        qry_bf, wt_val, b_val, v_bf, R_ROWS, 256, 256);
    // 3. off = q @ W_off + b_off -> cb (f32)
    gemm_mfma_kernel<false, false><<<dim3(MB, 2), blk, 0, stream>>>(
        q_bf, wt_off, b_off, cb, R_ROWS, 256, 256);
    // 4. logits = q @ W_attn + b_attn (f32, softmax fused into deform)
    gemm_mfma_kernel<false, false><<<dim3(MB, 1), blk, 0, stream>>>(
        q_bf, wt_attn, b_attn, logits, R_ROWS, 128, 256);
    // 5. deformable sampling (+softmax) -> samp_bf
    deform_sample_kernel<<<(R_ROWS * NHEAD + 63) / 64, blk, 0, stream>>>(
        v_bf, cb, logits, vr, samp_bf);
    // 6. attn_out = sampled @ W_out + b_out -> cb (f32)
    gemm_mfma_kernel<false, false><<<dim3(MB, 2), blk, 0, stream>>>(
        samp_bf, wt_out, b_out, cb, R_ROWS, 256, 256);
    // 7. x = LN(query + attn_out) -> xb (f32) + samp_bf (bf16, reused as x_bf)
    add_ln_kernel<true><<<R_ROWS, blk, 0, stream>>>(query, cb, ln1g, ln1b, xb, samp_bf);
    // 8. h = relu(x @ W1 + b1) -> h_bf (overlays q_bf/qry_bf/v_bf/logits, all dead)
    gemm_mfma_kernel<true, true><<<dim3(MB, 8), blk, 0, stream>>>(
        samp_bf, wt_w1, b1, h_bf, R_ROWS, 1024, 256);
    // 9. f = h @ W2 + b2 -> cb (f32)
    gemm_mfma_kernel<false, false><<<dim3(MB, 2), blk, 0, stream>>>(
        h_bf, wt_w2, b2, cb, R_ROWS, 256, 1024);
    // 10. out = LN(x + f)
    add_ln_kernel<false><<<R_ROWS, blk, 0, stream>>>(xb, cb, ln2g, ln2b, out, nullptr);
}

// Round 4
// 344.903 us; speedup vs baseline: 3.1718x; 1.0918x over previous
//
#include <hip/hip_runtime.h>
#include <math.h>

#define R_ROWS 26588
#define S_TOT  13294
#define NHEAD  8
#define NLVL   4
#define EPSF   1e-5f

typedef __attribute__((ext_vector_type(8))) short short8;
typedef __attribute__((ext_vector_type(4))) float f32x4;
typedef __attribute__((ext_vector_type(2))) float f32x2;
typedef unsigned short ushort_t;

__device__ __forceinline__ unsigned short f2bf(float f) {
    unsigned int u = __builtin_bit_cast(unsigned int, f);
    unsigned int r = (u + 0x7FFFu + ((u >> 16) & 1u)) >> 16;   // RNE
    return (unsigned short)r;
}

// ---------------------------------------------------------------------------
// All six weight transposes in ONE kernel. src f32 [K][N] -> dst bf16 [N][K].
// 32x32 tiles; block = 256 = 32x8.
// tile bases: val 0, off 64, attn 128, out 160, W1 224, W2 480; total 736.
// ---------------------------------------------------------------------------
__global__ __launch_bounds__(256) void transpose_all_kernel(
    const float* __restrict__ W_val, const float* __restrict__ W_off,
    const float* __restrict__ W_attn, const float* __restrict__ W_out,
    const float* __restrict__ W1, const float* __restrict__ W2,
    ushort_t* __restrict__ wt_val, ushort_t* __restrict__ wt_off,
    ushort_t* __restrict__ wt_attn, ushort_t* __restrict__ wt_out,
    ushort_t* __restrict__ wt_w1, ushort_t* __restrict__ wt_w2)
{
    int bid = blockIdx.x;
    const float* src; ushort_t* dst; int K, N, t;
    if (bid < 64)       { src = W_val;  dst = wt_val;  K = 256;  N = 256;  t = bid; }
    else if (bid < 128) { src = W_off;  dst = wt_off;  K = 256;  N = 256;  t = bid - 64; }
    else if (bid < 160) { src = W_attn; dst = wt_attn; K = 256;  N = 128;  t = bid - 128; }
    else if (bid < 224) { src = W_out;  dst = wt_out;  K = 256;  N = 256;  t = bid - 160; }
    else if (bid < 480) { src = W1;     dst = wt_w1;   K = 256;  N = 1024; t = bid - 224; }
    else                { src = W2;     dst = wt_w2;   K = 1024; N = 256;  t = bid - 480; }
    int nt = N / 32;
    int bn = (t % nt) * 32, bk = (t / nt) * 32;

    __shared__ ushort_t tt[32][33];
    int x = threadIdx.x & 31;
    int y = threadIdx.x >> 5;
#pragma unroll
    for (int i = 0; i < 4; ++i) {
        int k = y + i * 8;
        tt[x][k] = f2bf(src[(long)(bk + k) * N + bn + x]);
    }
    __syncthreads();
#pragma unroll
    for (int i = 0; i < 4; ++i) {
        int n = y + i * 8;
        dst[(long)(bn + n) * K + bk + x] = tt[n][x];
    }
}

// ---------------------------------------------------------------------------
// qry_bf = bf16(query), qsum_bf = bf16(query + qpos). 4 elem/thread.
// ---------------------------------------------------------------------------
__global__ __launch_bounds__(256) void addcvt_kernel(
    const float* __restrict__ q, const float* __restrict__ p,
    ushort_t* __restrict__ qry_bf, ushort_t* __restrict__ qsum_bf, int n4)
{
    int i = blockIdx.x * 256 + threadIdx.x;
    if (i >= n4) return;
    float4 a = ((const float4*)q)[i];
    float4 b = ((const float4*)p)[i];
    uint2 qa, qs;
    qa.x = (unsigned)f2bf(a.x) | ((unsigned)f2bf(a.y) << 16);
    qa.y = (unsigned)f2bf(a.z) | ((unsigned)f2bf(a.w) << 16);
    qs.x = (unsigned)f2bf(a.x + b.x) | ((unsigned)f2bf(a.y + b.y) << 16);
    qs.y = (unsigned)f2bf(a.z + b.z) | ((unsigned)f2bf(a.w + b.w) << 16);
    ((uint2*)qry_bf)[i] = qa;
    ((uint2*)qsum_bf)[i] = qs;
}

// ---------------------------------------------------------------------------
// Shared GEMM body: C[M,N] = A[M,K](bf16) @ Wt^T + bias.  Wt bf16 [N][K].
// Block 256 = 4 waves arranged 2x2; block tile 128x128; wave tile 64x64.
// Per k32 per wave: 4 A-frags + 4 B-frags (8 ds_read_b128) -> 16 MFMA.
// ---------------------------------------------------------------------------
__device__ __forceinline__ void gemm_body(
    ushort_t (*As)[40], ushort_t (*Bs)[40],
    const ushort_t* __restrict__ A, const ushort_t* __restrict__ Wt,
    const float* __restrict__ bias, void* __restrict__ Cv,
    int M, int N, int K, int bm, int bn, bool out_bf16, bool relu)
{
    const int tid  = threadIdx.x;
    const int wave = tid >> 6;
    const int lane = tid & 63;
    const int l15  = lane & 15;
    const int quad = lane >> 4;
    const int wm   = (wave >> 1) * 64;
    const int wn   = (wave & 1) * 64;
    const int kq   = (tid & 3) * 8;
    const int r0   = tid >> 2;          // 0..63

    f32x4 acc[4][4];
#pragma unroll
    for (int i = 0; i < 4; ++i)
#pragma unroll
        for (int j = 0; j < 4; ++j) acc[i][j] = (f32x4)0.0f;

    for (int k0 = 0; k0 < K; k0 += 32) {
#pragma unroll
        for (int i = 0; i < 2; ++i) {
            int r = r0 + i * 64;
            int m = bm + r;
            uint4 val; val.x = val.y = val.z = val.w = 0u;
            if (m < M) val = *(const uint4*)&A[(long)m * K + k0 + kq];
            *(uint4*)&As[r][kq] = val;
        }
#pragma unroll
        for (int i = 0; i < 2; ++i) {
            int n = r0 + i * 64;
            *(uint4*)&Bs[n][kq] = *(const uint4*)&Wt[(long)(bn + n) * K + k0 + kq];
        }
        __syncthreads();

        short8 af[4], bf[4];
#pragma unroll
        for (int mi = 0; mi < 4; ++mi)
            af[mi] = *(const short8*)&As[wm + mi * 16 + l15][quad * 8];
#pragma unroll
        for (int ni = 0; ni < 4; ++ni)
            bf[ni] = *(const short8*)&Bs[wn + ni * 16 + l15][quad * 8];
#pragma unroll
        for (int mi = 0; mi < 4; ++mi)
#pragma unroll
            for (int ni = 0; ni < 4; ++ni)
                acc[mi][ni] = __builtin_amdgcn_mfma_f32_16x16x32_bf16(
                    af[mi], bf[ni], acc[mi][ni], 0, 0, 0);
        __syncthreads();
    }

#pragma unroll
    for (int mi = 0; mi < 4; ++mi) {
#pragma unroll
        for (int r = 0; r < 4; ++r) {
            int row = bm + wm + mi * 16 + quad * 4 + r;
            if (row >= M) continue;
#pragma unroll
            for (int ni = 0; ni < 4; ++ni) {
                int col = bn + wn + ni * 16 + l15;
                float vv = acc[mi][ni][r] + bias[col];
                if (relu) vv = fmaxf(vv, 0.f);
                if (out_bf16)
                    ((ushort_t*)Cv)[(long)row * N + col] = f2bf(vv);
                else
                    ((float*)Cv)[(long)row * N + col] = vv;
            }
        }
    }
}

template<bool OUT_BF16, bool RELU>
__global__ __launch_bounds__(256) void gemm_mfma_kernel(
    const ushort_t* __restrict__ A, const ushort_t* __restrict__ Wt,
    const float* __restrict__ bias, void* __restrict__ Cv,
    int M, int N, int K)
{
    __shared__ ushort_t As[128][40];
    __shared__ ushort_t Bs[128][40];
    gemm_body(As, Bs, A, Wt, bias, Cv, M, N, K,
              blockIdx.x * 128, blockIdx.y * 128, OUT_BF16, RELU);
}

// Combined val/off/attn projections in one launch. grid = (MB, 5).
// y 0-1: v = qry @ Wv -> v_bf (bf16, N=256); y 2-3: off = q @ Woff -> cb (f32);
// y 4: logits = q @ Wattn -> logits (f32, N=128)
__global__ __launch_bounds__(256) void proj_kernel(
    const ushort_t* __restrict__ qry_bf, const ushort_t* __restrict__ q_bf,
    const ushort_t* __restrict__ wt_val, const ushort_t* __restrict__ wt_off,
    const ushort_t* __restrict__ wt_attn,
    const float* __restrict__ b_val, const float* __restrict__ b_off,
    const float* __restrict__ b_attn,
    ushort_t* __restrict__ v_bf, float* __restrict__ cb, float* __restrict__ logits)
{
    __shared__ ushort_t As[128][40];
    __shared__ ushort_t Bs[128][40];
    int y = blockIdx.y;
    const ushort_t* A; const ushort_t* Wt; const float* bias;
    void* C; bool outbf; int N, bn;
    if (y < 2)      { A = qry_bf; Wt = wt_val;  bias = b_val;  C = v_bf;   outbf = true;  N = 256; bn = y * 128; }
    else if (y < 4) { A = q_bf;   Wt = wt_off;  bias = b_off;  C = cb;     outbf = false; N = 256; bn = (y - 2) * 128; }
    else            { A = q_bf;   Wt = wt_attn; bias = b_attn; C = logits; outbf = false; N = 128; bn = 0; }
    gemm_body(As, Bs, A, Wt, bias, C, R_ROWS, N, 256, blockIdx.x * 128, bn, outbf, false);
}

// ---------------------------------------------------------------------------
// Deformable sampling + fused softmax, lane-specialized.
// 4 lanes per (row,head) group; lane j owns level j's 4 points (geometry) and
// channels 8j..8j+7 (accumulation). Broadcast via __shfl within the quad.
// ---------------------------------------------------------------------------
__global__ __launch_bounds__(256) void deform_sample_kernel(
    const ushort_t* __restrict__ v, const float* __restrict__ off,
    const float* __restrict__ logits, const float* __restrict__ vr,
    ushort_t* __restrict__ out)
{
    const int Hs_[4] = {100, 50, 25, 13};
    const int S0_[4] = {0, 10000, 12500, 13125};

    int grp = blockIdx.x * 64 + (threadIdx.x >> 2);
    int j   = threadIdx.x & 3;
    if (grp >= R_ROWS * NHEAD) return;
    int h = grp & 7;
    int r = grp >> 3;
    int b = (r >= S_TOT) ? 1 : 0;
    int s = r - b * S_TOT;

    int lq = (s < 10000) ? 0 : (s < 12500) ? 1 : (s < 13125) ? 2 : 3;
    int t  = s - S0_[lq];
    int Wq = Hs_[lq];
    int iy = t / Wq;
    int jx = t - iy * Wq;
    float vx = vr[(b * NLVL + lq) * 2 + 0];
    float vy = vr[(b * NLVL + lq) * 2 + 1];
    float rx = (jx + 0.5f) / (vx * (float)Wq);
    float ry = (iy + 0.5f) / (vy * (float)Wq);

    // vectorized loads: lane j gets level j's offsets + logits
    const float* offp = off + (long)r * 256 + h * 32;
    float4 oa = ((const float4*)offp)[2 * j];      // points 4j, 4j+1: (ox,oy,ox,oy)
    float4 ob = ((const float4*)offp)[2 * j + 1];  // points 4j+2, 4j+3
    float4 lg = ((const float4*)(logits + (long)grp * 16))[j];

    // cooperative softmax over 16 logits
    float mx = fmaxf(fmaxf(lg.x, lg.y), fmaxf(lg.z, lg.w));
    mx = fmaxf(mx, __shfl_xor(mx, 1));
    mx = fmaxf(mx, __shfl_xor(mx, 2));
    float e0 = __expf(lg.x - mx), e1 = __expf(lg.y - mx);
    float e2 = __expf(lg.z - mx), e3 = __expf(lg.w - mx);
    float sum = e0 + e1 + e2 + e3;
    sum += __shfl_xor(sum, 1);
    sum += __shfl_xor(sum, 2);
    float inv = 1.f / sum;

    // own-level geometry for 4 points: weights (validity-folded) + clamped idx
    const int   H  = Hs_[j];
    const float fH = (float)H;
    const int   s0 = S0_[j];
    float oxs[4] = {oa.x, oa.z, ob.x, ob.z};
    float oys[4] = {oa.y, oa.w, ob.y, ob.w};
    float wts[4] = {e0 * inv, e1 * inv, e2 * inv, e3 * inv};
    float pw0[4], pw1[4], pw2[4], pw3[4];
    int   pi0[4], pi1[4], pi2[4], pi3[4];
#pragma unroll
    for (int i = 0; i < 4; ++i) {
        float x = rx * fH + oxs[i] - 0.5f;
        float y = ry * fH + oys[i] - 0.5f;
        float xf = floorf(x), yf = floorf(y);
        float lx = x - xf, ly = y - yf;
        int x0 = (int)xf, y0 = (int)yf;
        bool xv0 = (x0 >= 0) & (x0 < H);
        bool xv1 = (x0 >= -1) & (x0 < H - 1);
        bool yv0 = (y0 >= 0) & (y0 < H);
        bool yv1 = (y0 >= -1) & (y0 < H - 1);
        float w = wts[i];
        pw0[i] = (xv0 & yv0) ? (1.f - lx) * (1.f - ly) * w : 0.f;
        pw1[i] = (xv1 & yv0) ? lx * (1.f - ly) * w : 0.f;
        pw2[i] = (xv0 & yv1) ? (1.f - lx) * ly * w : 0.f;
        pw3[i] = (xv1 & yv1) ? lx * ly * w : 0.f;
        int xc0 = min(max(x0, 0), H - 1), xc1 = min(max(x0 + 1, 0), H - 1);
        int yc0 = min(max(y0, 0), H - 1), yc1 = min(max(y0 + 1, 0), H - 1);
        pi0[i] = s0 + yc0 * H + xc0;
        pi1[i] = s0 + yc0 * H + xc1;
        pi2[i] = s0 + yc1 * H + xc0;
        pi3[i] = s0 + yc1 * H + xc1;
    }

    const ushort_t* vb = v + ((long)b * S_TOT) * 256 + h * 32 + j * 8;
    f32x2 acc2[4];
#pragma unroll
    for (int c = 0; c < 4; ++c) acc2[c] = (f32x2)0.0f;

#define ACC_CORNER(IDX, WGT) do {                                            \
        uint4 g = *(const uint4*)&vb[(long)(IDX) * 256];                     \
        unsigned uu0 = g.x, uu1 = g.y, uu2 = g.z, uu3 = g.w;                 \
        f32x2 gv;                                                            \
        gv.x = __builtin_bit_cast(float, uu0 << 16);                         \
        gv.y = __builtin_bit_cast(float, uu0 & 0xFFFF0000u);                 \
        acc2[0] += gv * (WGT);                                               \
        gv.x = __builtin_bit_cast(float, uu1 << 16);                         \
        gv.y = __builtin_bit_cast(float, uu1 & 0xFFFF0000u);                 \
        acc2[1] += gv * (WGT);                                               \
        gv.x = __builtin_bit_cast(float, uu2 << 16);                         \
        gv.y = __builtin_bit_cast(float, uu2 & 0xFFFF0000u);                 \
        acc2[2] += gv * (WGT);                                               \
        gv.x = __builtin_bit_cast(float, uu3 << 16);                         \
        gv.y = __builtin_bit_cast(float, uu3 & 0xFFFF0000u);                 \
        acc2[3] += gv * (WGT);                                               \
    } while (0)

#pragma unroll
    for (int i = 0; i < 4; ++i) {
#pragma unroll
        for (int j2 = 0; j2 < 4; ++j2) {
            float w00 = __shfl(pw0[i], j2, 4);
            float w01 = __shfl(pw1[i], j2, 4);
            float w10 = __shfl(pw2[i], j2, 4);
            float w11 = __shfl(pw3[i], j2, 4);
            int   i00 = __shfl(pi0[i], j2, 4);
            int   i01 = __shfl(pi1[i], j2, 4);
            int   i10 = __shfl(pi2[i], j2, 4);
            int   i11 = __shfl(pi3[i], j2, 4);
            ACC_CORNER(i00, w00);
            ACC_CORNER(i01, w01);
            ACC_CORNER(i10, w10);
            ACC_CORNER(i11, w11);
        }
    }
#undef ACC_CORNER

    uint4 o;
    o.x = (unsigned)f2bf(acc2[0].x) | ((unsigned)f2bf(acc2[0].y) << 16);
    o.y = (unsigned)f2bf(acc2[1].x) | ((unsigned)f2bf(acc2[1].y) << 16);
    o.z = (unsigned)f2bf(acc2[2].x) | ((unsigned)f2bf(acc2[2].y) << 16);
    o.w = (unsigned)f2bf(acc2[3].x) | ((unsigned)f2bf(acc2[3].y) << 16);
    *(uint4*)&out[(long)r * 256 + h * 32 + j * 8] = o;
}

// ---------------------------------------------------------------------------
// out = LayerNorm(a + b); optionally also emit bf16 copy
// ---------------------------------------------------------------------------
template<bool DUAL>
__global__ __launch_bounds__(256) void add_ln_kernel(
    const float* __restrict__ a, const float* __restrict__ b,
    const float* __restrict__ g, const float* __restrict__ beta,
    float* __restrict__ outf, ushort_t* __restrict__ outb)
{
    int row = blockIdx.x;
    int tid = threadIdx.x;
    float x = a[(long)row * 256 + tid] + b[(long)row * 256 + tid];
    float s1 = x, s2 = x * x;
#pragma unroll
    for (int o = 32; o > 0; o >>= 1) {
        s1 += __shfl_down(s1, o, 64);
        s2 += __shfl_down(s2, o, 64);
    }
    __shared__ float sh1[4], sh2[4];
    int w = tid >> 6;
    if ((tid & 63) == 0) { sh1[w] = s1; sh2[w] = s2; }
    __syncthreads();
    float t1 = sh1[0] + sh1[1] + sh1[2] + sh1[3];
    float t2 = sh2[0] + sh2[1] + sh2[2] + sh2[3];
    float mean = t1 * (1.f / 256.f);
    float var  = t2 * (1.f / 256.f) - mean * mean;
    float inv  = rsqrtf(var + EPSF);
    float y = (x - mean) * inv * g[tid] + beta[tid];
    outf[(long)row * 256 + tid] = y;
    if (DUAL) outb[(long)row * 256 + tid] = f2bf(y);
}

// ---------------------------------------------------------------------------
extern "C" void kernel_launch(void* const* d_in, const int* in_sizes, int n_in,
                              void* d_out, int out_size, void* d_ws, size_t ws_size,
                              hipStream_t stream)
{
    const float* query  = (const float*)d_in[0];
    const float* qpos   = (const float*)d_in[1];
    const float* vr     = (const float*)d_in[2];
    const float* W_off  = (const float*)d_in[5];
    const float* b_off  = (const float*)d_in[6];
    const float* W_attn = (const float*)d_in[7];
    const float* b_attn = (const float*)d_in[8];
    const float* W_val  = (const float*)d_in[9];
    const float* b_val  = (const float*)d_in[10];
    const float* W_out  = (const float*)d_in[11];
    const float* b_out  = (const float*)d_in[12];
    const float* ln1g   = (const float*)d_in[13];
    const float* ln1b   = (const float*)d_in[14];
    const float* W1     = (const float*)d_in[15];
    const float* b1     = (const float*)d_in[16];
    const float* W2     = (const float*)d_in[17];
    const float* b2     = (const float*)d_in[18];
    const float* ln2g   = (const float*)d_in[19];
    const float* ln2b   = (const float*)d_in[20];
    float* out = (float*)d_out;

    float* ws = (float*)d_ws;
    const long R128 = (long)R_ROWS * 128;
    ushort_t* q_bf    = (ushort_t*)(ws);                 // R x 256 bf16
    ushort_t* qry_bf  = (ushort_t*)(ws + R128);          // R x 256 bf16
    ushort_t* v_bf    = (ushort_t*)(ws + 2 * R128);      // R x 256 bf16
    float*    logits  = ws + 3 * R128;                   // R x 128 f32
    ushort_t* h_bf    = (ushort_t*)(ws);                 // R x 1024 bf16 (overlays the 4 above)
    float*    cb      = ws + 4 * R128;                   // R x 256 f32: off -> attn_out -> f
    ushort_t* samp_bf = (ushort_t*)(ws + 6 * R128);      // R x 256 bf16: sampled -> x_bf
    float*    xb      = ws + 7 * R128;                   // R x 256 f32: x (LN1 out)
    ushort_t* wt      = (ushort_t*)(ws + 9 * R128);
    ushort_t* wt_val  = wt;                 // 256x256
    ushort_t* wt_off  = wt + 65536;         // 256x256
    ushort_t* wt_attn = wt + 131072;        // 128x256
    ushort_t* wt_out  = wt + 163840;        // 256x256
    ushort_t* wt_w1   = wt + 229376;        // 1024x256
    ushort_t* wt_w2   = wt + 491520;        // 256x1024

    dim3 blk(256);
    const int MB = (R_ROWS + 127) / 128;   // 208

    // 1. all weight transposes (one launch)
    transpose_all_kernel<<<736, blk, 0, stream>>>(
        W_val, W_off, W_attn, W_out, W1, W2,
        wt_val, wt_off, wt_attn, wt_out, wt_w1, wt_w2);
    // 2. qry_bf = bf16(query); q_bf = bf16(query + qpos)
    addcvt_kernel<<<(R_ROWS * 64 + 255) / 256, blk, 0, stream>>>(
        query, qpos, qry_bf, q_bf, R_ROWS * 64);
    // 3. val + off + attn projections (one launch)
    proj_kernel<<<dim3(MB, 5), blk, 0, stream>>>(
        qry_bf, q_bf, wt_val, wt_off, wt_attn, b_val, b_off, b_attn,
        v_bf, cb, logits);
    // 4. deformable sampling (+softmax) -> samp_bf
    deform_sample_kernel<<<(R_ROWS * NHEAD + 63) / 64, blk, 0, stream>>>(
        v_bf, cb, logits, vr, samp_bf);
    // 5. attn_out = sampled @ W_out + b_out -> cb (f32)
    gemm_mfma_kernel<false, false><<<dim3(MB, 2), blk, 0, stream>>>(
        samp_bf, wt_out, b_out, cb, R_ROWS, 256, 256);
    // 6. x = LN(query + attn_out) -> xb (f32) + samp_bf (bf16 x)
    add_ln_kernel<true><<<R_ROWS, blk, 0, stream>>>(query, cb, ln1g, ln1b, xb, samp_bf);
    // 7. h = relu(x @ W1 + b1) -> h_bf
    gemm_mfma_kernel<true, true><<<dim3(MB, 8), blk, 0, stream>>>(
        samp_bf, wt_w1, b1, h_bf, R_ROWS, 1024, 256);
    // 8. f = h @ W2 + b2 -> cb (f32)
    gemm_mfma_kernel<false, false><<<dim3(MB, 2), blk, 0, stream>>>(
        h_bf, wt_w2, b2, cb, R_ROWS, 256, 1024);
    // 9. out = LN(x + f)
    add_ln_kernel<false><<<R_ROWS, blk, 0, stream>>>(xb, cb, ln2g, ln2b, out, nullptr);
}

// Round 5
// 333.445 us; speedup vs baseline: 3.2808x; 1.0344x over previous
//
#include <hip/hip_runtime.h>
#include <math.h>

#define R_ROWS 26588
#define S_TOT  13294
#define NHEAD  8
#define NLVL   4
#define EPSF   1e-5f

typedef __attribute__((ext_vector_type(8))) short short8;
typedef __attribute__((ext_vector_type(4))) float f32x4;
typedef __attribute__((ext_vector_type(2))) float f32x2;
typedef unsigned short ushort_t;

__device__ __forceinline__ unsigned short f2bf(float f) {
    unsigned int u = __builtin_bit_cast(unsigned int, f);
    unsigned int r = (u + 0x7FFFu + ((u >> 16) & 1u)) >> 16;   // RNE
    return (unsigned short)r;
}

// ---------------------------------------------------------------------------
// All six weight transposes in ONE kernel. src f32 [K][N] -> dst bf16 [N][K].
// ---------------------------------------------------------------------------
__global__ __launch_bounds__(256) void transpose_all_kernel(
    const float* __restrict__ W_val, const float* __restrict__ W_off,
    const float* __restrict__ W_attn, const float* __restrict__ W_out,
    const float* __restrict__ W1, const float* __restrict__ W2,
    ushort_t* __restrict__ wt_val, ushort_t* __restrict__ wt_off,
    ushort_t* __restrict__ wt_attn, ushort_t* __restrict__ wt_out,
    ushort_t* __restrict__ wt_w1, ushort_t* __restrict__ wt_w2)
{
    int bid = blockIdx.x;
    const float* src; ushort_t* dst; int K, N, t;
    if (bid < 64)       { src = W_val;  dst = wt_val;  K = 256;  N = 256;  t = bid; }
    else if (bid < 128) { src = W_off;  dst = wt_off;  K = 256;  N = 256;  t = bid - 64; }
    else if (bid < 160) { src = W_attn; dst = wt_attn; K = 256;  N = 128;  t = bid - 128; }
    else if (bid < 224) { src = W_out;  dst = wt_out;  K = 256;  N = 256;  t = bid - 160; }
    else if (bid < 480) { src = W1;     dst = wt_w1;   K = 256;  N = 1024; t = bid - 224; }
    else                { src = W2;     dst = wt_w2;   K = 1024; N = 256;  t = bid - 480; }
    int nt = N / 32;
    int bn = (t % nt) * 32, bk = (t / nt) * 32;

    __shared__ ushort_t tt[32][33];
    int x = threadIdx.x & 31;
    int y = threadIdx.x >> 5;
#pragma unroll
    for (int i = 0; i < 4; ++i) {
        int k = y + i * 8;
        tt[x][k] = f2bf(src[(long)(bk + k) * N + bn + x]);
    }
    __syncthreads();
#pragma unroll
    for (int i = 0; i < 4; ++i) {
        int n = y + i * 8;
        dst[(long)(bn + n) * K + bk + x] = tt[n][x];
    }
}

// ---------------------------------------------------------------------------
// qry_bf = bf16(query), qsum_bf = bf16(query + qpos). 4 elem/thread.
// ---------------------------------------------------------------------------
__global__ __launch_bounds__(256) void addcvt_kernel(
    const float* __restrict__ q, const float* __restrict__ p,
    ushort_t* __restrict__ qry_bf, ushort_t* __restrict__ qsum_bf, int n4)
{
    int i = blockIdx.x * 256 + threadIdx.x;
    if (i >= n4) return;
    float4 a = ((const float4*)q)[i];
    float4 b = ((const float4*)p)[i];
    uint2 qa, qs;
    qa.x = (unsigned)f2bf(a.x) | ((unsigned)f2bf(a.y) << 16);
    qa.y = (unsigned)f2bf(a.z) | ((unsigned)f2bf(a.w) << 16);
    qs.x = (unsigned)f2bf(a.x + b.x) | ((unsigned)f2bf(a.y + b.y) << 16);
    qs.y = (unsigned)f2bf(a.z + b.z) | ((unsigned)f2bf(a.w + b.w) << 16);
    ((uint2*)qry_bf)[i] = qa;
    ((uint2*)qsum_bf)[i] = qs;
}

// ---------------------------------------------------------------------------
// Async-staged GEMM body: C[M,N] = A[M,K](bf16) @ Wt^T + bias.  Wt bf16 [N][K].
// Block 256 = 4 waves (2x2); block tile 128x128; wave tile 64x64; BK=32.
// Staging via global_load_lds width=16 into unpadded [128][32] LDS tiles.
// Bank conflicts broken by XOR quad swizzle applied on the GLOBAL side:
//   physical slot quadS holds logical k-quad quadS ^ ((row>>1)&3)
// -> frag ds_read_b128: rows 0..7 hit 8 distinct bank-starts, 2-way = free.
// ---------------------------------------------------------------------------
__device__ __forceinline__ void stage32_async(
    const ushort_t* __restrict__ src_row0, int ld, int k0,
    ushort_t* lds, int wave, int lane)
{
#pragma unroll
    for (int inst = 0; inst < 2; ++inst) {
        int base_row = wave * 32 + inst * 16;
        int r = base_row + (lane >> 2);
        int quadS = lane & 3;
        int quadG = quadS ^ ((r >> 1) & 3);
        const ushort_t* gp = src_row0 + (long)r * ld + k0 + quadG * 8;
        __builtin_amdgcn_global_load_lds(
            (const __attribute__((address_space(1))) unsigned int*)gp,
            (__attribute__((address_space(3))) unsigned int*)&lds[base_row * 32],
            16, 0, 0);
    }
}

__device__ __forceinline__ void gemm_body(
    ushort_t* As, ushort_t* Bs,   // flat [128*32]
    const ushort_t* __restrict__ A, const ushort_t* __restrict__ Wt,
    const float* __restrict__ bias, void* __restrict__ Cv,
    int M, int N, int K, int bm, int bn, bool out_bf16, bool relu)
{
    const int tid  = threadIdx.x;
    const int wave = tid >> 6;
    const int lane = tid & 63;
    const int l15  = lane & 15;
    const int quad = lane >> 4;
    const int wm   = (wave >> 1) * 64;
    const int wn   = (wave & 1) * 64;

    const ushort_t* Arow = A + (long)bm * K;
    const ushort_t* Brow = Wt + (long)bn * K;

    f32x4 acc[4][4];
#pragma unroll
    for (int i = 0; i < 4; ++i)
#pragma unroll
        for (int j = 0; j < 4; ++j) acc[i][j] = (f32x4)0.0f;

    // precompute swizzled LDS offsets for frag reads (in ushort units)
    int aoff[4], boff[4];
#pragma unroll
    for (int mi = 0; mi < 4; ++mi) {
        int r = wm + mi * 16 + l15;
        aoff[mi] = r * 32 + (quad ^ ((r >> 1) & 3)) * 8;
    }
#pragma unroll
    for (int ni = 0; ni < 4; ++ni) {
        int r = wn + ni * 16 + l15;
        boff[ni] = r * 32 + (quad ^ ((r >> 1) & 3)) * 8;
    }

    for (int k0 = 0; k0 < K; k0 += 32) {
        stage32_async(Arow, K, k0, As, wave, lane);
        stage32_async(Brow, K, k0, Bs, wave, lane);
        __syncthreads();

        short8 af[4], bf[4];
#pragma unroll
        for (int mi = 0; mi < 4; ++mi) af[mi] = *(const short8*)&As[aoff[mi]];
#pragma unroll
        for (int ni = 0; ni < 4; ++ni) bf[ni] = *(const short8*)&Bs[boff[ni]];
#pragma unroll
        for (int mi = 0; mi < 4; ++mi)
#pragma unroll
            for (int ni = 0; ni < 4; ++ni)
                acc[mi][ni] = __builtin_amdgcn_mfma_f32_16x16x32_bf16(
                    af[mi], bf[ni], acc[mi][ni], 0, 0, 0);
        __syncthreads();
    }

#pragma unroll
    for (int mi = 0; mi < 4; ++mi) {
#pragma unroll
        for (int r = 0; r < 4; ++r) {
            int row = bm + wm + mi * 16 + quad * 4 + r;
            if (row >= M) continue;
#pragma unroll
            for (int ni = 0; ni < 4; ++ni) {
                int col = bn + wn + ni * 16 + l15;
                float vv = acc[mi][ni][r] + bias[col];
                if (relu) vv = fmaxf(vv, 0.f);
                if (out_bf16)
                    ((ushort_t*)Cv)[(long)row * N + col] = f2bf(vv);
                else
                    ((float*)Cv)[(long)row * N + col] = vv;
            }
        }
    }
}

template<bool OUT_BF16, bool RELU>
__global__ __launch_bounds__(256) void gemm_mfma_kernel(
    const ushort_t* __restrict__ A, const ushort_t* __restrict__ Wt,
    const float* __restrict__ bias, void* __restrict__ Cv,
    int M, int N, int K)
{
    __shared__ ushort_t As[128 * 32];
    __shared__ ushort_t Bs[128 * 32];
    gemm_body(As, Bs, A, Wt, bias, Cv, M, N, K,
              blockIdx.x * 128, blockIdx.y * 128, OUT_BF16, RELU);
}

// Combined val/off/attn projections. grid = (MB, 5).
__global__ __launch_bounds__(256) void proj_kernel(
    const ushort_t* __restrict__ qry_bf, const ushort_t* __restrict__ q_bf,
    const ushort_t* __restrict__ wt_val, const ushort_t* __restrict__ wt_off,
    const ushort_t* __restrict__ wt_attn,
    const float* __restrict__ b_val, const float* __restrict__ b_off,
    const float* __restrict__ b_attn,
    ushort_t* __restrict__ v_bf, float* __restrict__ cb, float* __restrict__ logits)
{
    __shared__ ushort_t As[128 * 32];
    __shared__ ushort_t Bs[128 * 32];
    int y = blockIdx.y;
    const ushort_t* A; const ushort_t* Wt; const float* bias;
    void* C; bool outbf; int N, bn;
    if (y < 2)      { A = qry_bf; Wt = wt_val;  bias = b_val;  C = v_bf;   outbf = true;  N = 256; bn = y * 128; }
    else if (y < 4) { A = q_bf;   Wt = wt_off;  bias = b_off;  C = cb;     outbf = false; N = 256; bn = (y - 2) * 128; }
    else            { A = q_bf;   Wt = wt_attn; bias = b_attn; C = logits; outbf = false; N = 128; bn = 0; }
    gemm_body(As, Bs, A, Wt, bias, C, R_ROWS, N, 256, blockIdx.x * 128, bn, outbf, false);
}

// ---------------------------------------------------------------------------
// Deformable sampling + fused softmax, lane-specialized (unchanged from R3).
// ---------------------------------------------------------------------------
__global__ __launch_bounds__(256) void deform_sample_kernel(
    const ushort_t* __restrict__ v, const float* __restrict__ off,
    const float* __restrict__ logits, const float* __restrict__ vr,
    ushort_t* __restrict__ out)
{
    const int Hs_[4] = {100, 50, 25, 13};
    const int S0_[4] = {0, 10000, 12500, 13125};

    int grp = blockIdx.x * 64 + (threadIdx.x >> 2);
    int j   = threadIdx.x & 3;
    if (grp >= R_ROWS * NHEAD) return;
    int h = grp & 7;
    int r = grp >> 3;
    int b = (r >= S_TOT) ? 1 : 0;
    int s = r - b * S_TOT;

    int lq = (s < 10000) ? 0 : (s < 12500) ? 1 : (s < 13125) ? 2 : 3;
    int t  = s - S0_[lq];
    int Wq = Hs_[lq];
    int iy = t / Wq;
    int jx = t - iy * Wq;
    float vx = vr[(b * NLVL + lq) * 2 + 0];
    float vy = vr[(b * NLVL + lq) * 2 + 1];
    float rx = (jx + 0.5f) / (vx * (float)Wq);
    float ry = (iy + 0.5f) / (vy * (float)Wq);

    const float* offp = off + (long)r * 256 + h * 32;
    float4 oa = ((const float4*)offp)[2 * j];
    float4 ob = ((const float4*)offp)[2 * j + 1];
    float4 lg = ((const float4*)(logits + (long)grp * 16))[j];

    float mx = fmaxf(fmaxf(lg.x, lg.y), fmaxf(lg.z, lg.w));
    mx = fmaxf(mx, __shfl_xor(mx, 1));
    mx = fmaxf(mx, __shfl_xor(mx, 2));
    float e0 = __expf(lg.x - mx), e1 = __expf(lg.y - mx);
    float e2 = __expf(lg.z - mx), e3 = __expf(lg.w - mx);
    float sum = e0 + e1 + e2 + e3;
    sum += __shfl_xor(sum, 1);
    sum += __shfl_xor(sum, 2);
    float inv = 1.f / sum;

    const int   H  = Hs_[j];
    const float fH = (float)H;
    const int   s0 = S0_[j];
    float oxs[4] = {oa.x, oa.z, ob.x, ob.z};
    float oys[4] = {oa.y, oa.w, ob.y, ob.w};
    float wts[4] = {e0 * inv, e1 * inv, e2 * inv, e3 * inv};
    float pw0[4], pw1[4], pw2[4], pw3[4];
    int   pi0[4], pi1[4], pi2[4], pi3[4];
#pragma unroll
    for (int i = 0; i < 4; ++i) {
        float x = rx * fH + oxs[i] - 0.5f;
        float y = ry * fH + oys[i] - 0.5f;
        float xf = floorf(x), yf = floorf(y);
        float lx = x - xf, ly = y - yf;
        int x0 = (int)xf, y0 = (int)yf;
        bool xv0 = (x0 >= 0) & (x0 < H);
        bool xv1 = (x0 >= -1) & (x0 < H - 1);
        bool yv0 = (y0 >= 0) & (y0 < H);
        bool yv1 = (y0 >= -1) & (y0 < H - 1);
        float w = wts[i];
        pw0[i] = (xv0 & yv0) ? (1.f - lx) * (1.f - ly) * w : 0.f;
        pw1[i] = (xv1 & yv0) ? lx * (1.f - ly) * w : 0.f;
        pw2[i] = (xv0 & yv1) ? (1.f - lx) * ly * w : 0.f;
        pw3[i] = (xv1 & yv1) ? lx * ly * w : 0.f;
        int xc0 = min(max(x0, 0), H - 1), xc1 = min(max(x0 + 1, 0), H - 1);
        int yc0 = min(max(y0, 0), H - 1), yc1 = min(max(y0 + 1, 0), H - 1);
        pi0[i] = s0 + yc0 * H + xc0;
        pi1[i] = s0 + yc0 * H + xc1;
        pi2[i] = s0 + yc1 * H + xc0;
        pi3[i] = s0 + yc1 * H + xc1;
    }

    const ushort_t* vb = v + ((long)b * S_TOT) * 256 + h * 32 + j * 8;
    f32x2 acc2[4];
#pragma unroll
    for (int c = 0; c < 4; ++c) acc2[c] = (f32x2)0.0f;

#define ACC_CORNER(IDX, WGT) do {                                            \
        uint4 g = *(const uint4*)&vb[(long)(IDX) * 256];                     \
        unsigned uu0 = g.x, uu1 = g.y, uu2 = g.z, uu3 = g.w;                 \
        f32x2 gv;                                                            \
        gv.x = __builtin_bit_cast(float, uu0 << 16);                         \
        gv.y = __builtin_bit_cast(float, uu0 & 0xFFFF0000u);                 \
        acc2[0] += gv * (WGT);                                               \
        gv.x = __builtin_bit_cast(float, uu1 << 16);                         \
        gv.y = __builtin_bit_cast(float, uu1 & 0xFFFF0000u);                 \
        acc2[1] += gv * (WGT);                                               \
        gv.x = __builtin_bit_cast(float, uu2 << 16);                         \
        gv.y = __builtin_bit_cast(float, uu2 & 0xFFFF0000u);                 \
        acc2[2] += gv * (WGT);                                               \
        gv.x = __builtin_bit_cast(float, uu3 << 16);                         \
        gv.y = __builtin_bit_cast(float, uu3 & 0xFFFF0000u);                 \
        acc2[3] += gv * (WGT);                                               \
    } while (0)

#pragma unroll
    for (int i = 0; i < 4; ++i) {
#pragma unroll
        for (int j2 = 0; j2 < 4; ++j2) {
            float w00 = __shfl(pw0[i], j2, 4);
            float w01 = __shfl(pw1[i], j2, 4);
            float w10 = __shfl(pw2[i], j2, 4);
            float w11 = __shfl(pw3[i], j2, 4);
            int   i00 = __shfl(pi0[i], j2, 4);
            int   i01 = __shfl(pi1[i], j2, 4);
            int   i10 = __shfl(pi2[i], j2, 4);
            int   i11 = __shfl(pi3[i], j2, 4);
            ACC_CORNER(i00, w00);
            ACC_CORNER(i01, w01);
            ACC_CORNER(i10, w10);
            ACC_CORNER(i11, w11);
        }
    }
#undef ACC_CORNER

    uint4 o;
    o.x = (unsigned)f2bf(acc2[0].x) | ((unsigned)f2bf(acc2[0].y) << 16);
    o.y = (unsigned)f2bf(acc2[1].x) | ((unsigned)f2bf(acc2[1].y) << 16);
    o.z = (unsigned)f2bf(acc2[2].x) | ((unsigned)f2bf(acc2[2].y) << 16);
    o.w = (unsigned)f2bf(acc2[3].x) | ((unsigned)f2bf(acc2[3].y) << 16);
    *(uint4*)&out[(long)r * 256 + h * 32 + j * 8] = o;
}

// ---------------------------------------------------------------------------
// out = LayerNorm(a + b); optionally also emit bf16 copy
// ---------------------------------------------------------------------------
template<bool DUAL>
__global__ __launch_bounds__(256) void add_ln_kernel(
    const float* __restrict__ a, const float* __restrict__ b,
    const float* __restrict__ g, const float* __restrict__ beta,
    float* __restrict__ outf, ushort_t* __restrict__ outb)
{
    int row = blockIdx.x;
    int tid = threadIdx.x;
    float x = a[(long)row * 256 + tid] + b[(long)row * 256 + tid];
    float s1 = x, s2 = x * x;
#pragma unroll
    for (int o = 32; o > 0; o >>= 1) {
        s1 += __shfl_down(s1, o, 64);
        s2 += __shfl_down(s2, o, 64);
    }
    __shared__ float sh1[4], sh2[4];
    int w = tid >> 6;
    if ((tid & 63) == 0) { sh1[w] = s1; sh2[w] = s2; }
    __syncthreads();
    float t1 = sh1[0] + sh1[1] + sh1[2] + sh1[3];
    float t2 = sh2[0] + sh2[1] + sh2[2] + sh2[3];
    float mean = t1 * (1.f / 256.f);
    float var  = t2 * (1.f / 256.f) - mean * mean;
    float inv  = rsqrtf(var + EPSF);
    float y = (x - mean) * inv * g[tid] + beta[tid];
    outf[(long)row * 256 + tid] = y;
    if (DUAL) outb[(long)row * 256 + tid] = f2bf(y);
}

// ---------------------------------------------------------------------------
extern "C" void kernel_launch(void* const* d_in, const int* in_sizes, int n_in,
                              void* d_out, int out_size, void* d_ws, size_t ws_size,
                              hipStream_t stream)
{
    const float* query  = (const float*)d_in[0];
    const float* qpos   = (const float*)d_in[1];
    const float* vr     = (const float*)d_in[2];
    const float* W_off  = (const float*)d_in[5];
    const float* b_off  = (const float*)d_in[6];
    const float* W_attn = (const float*)d_in[7];
    const float* b_attn = (const float*)d_in[8];
    const float* W_val  = (const float*)d_in[9];
    const float* b_val  = (const float*)d_in[10];
    const float* W_out  = (const float*)d_in[11];
    const float* b_out  = (const float*)d_in[12];
    const float* ln1g   = (const float*)d_in[13];
    const float* ln1b   = (const float*)d_in[14];
    const float* W1     = (const float*)d_in[15];
    const float* b1     = (const float*)d_in[16];
    const float* W2     = (const float*)d_in[17];
    const float* b2     = (const float*)d_in[18];
    const float* ln2g   = (const float*)d_in[19];
    const float* ln2b   = (const float*)d_in[20];
    float* out = (float*)d_out;

    float* ws = (float*)d_ws;
    const long R128 = (long)R_ROWS * 128;
    ushort_t* q_bf    = (ushort_t*)(ws);                 // R x 256 bf16
    ushort_t* qry_bf  = (ushort_t*)(ws + R128);          // R x 256 bf16
    ushort_t* v_bf    = (ushort_t*)(ws + 2 * R128);      // R x 256 bf16
    float*    logits  = ws + 3 * R128;                   // R x 128 f32
    ushort_t* h_bf    = (ushort_t*)(ws);                 // R x 1024 bf16 (overlays the 4 above)
    float*    cb      = ws + 4 * R128;                   // R x 256 f32: off -> attn_out -> f
    ushort_t* samp_bf = (ushort_t*)(ws + 6 * R128);      // R x 256 bf16: sampled -> x_bf
    float*    xb      = ws + 7 * R128;                   // R x 256 f32: x (LN1 out)
    ushort_t* wt      = (ushort_t*)(ws + 9 * R128);
    ushort_t* wt_val  = wt;                 // 256x256
    ushort_t* wt_off  = wt + 65536;         // 256x256
    ushort_t* wt_attn = wt + 131072;        // 128x256
    ushort_t* wt_out  = wt + 163840;        // 256x256
    ushort_t* wt_w1   = wt + 229376;        // 1024x256
    ushort_t* wt_w2   = wt + 491520;        // 256x1024

    dim3 blk(256);
    const int MB = (R_ROWS + 127) / 128;   // 208

    transpose_all_kernel<<<736, blk, 0, stream>>>(
        W_val, W_off, W_attn, W_out, W1, W2,
        wt_val, wt_off, wt_attn, wt_out, wt_w1, wt_w2);
    addcvt_kernel<<<(R_ROWS * 64 + 255) / 256, blk, 0, stream>>>(
        query, qpos, qry_bf, q_bf, R_ROWS * 64);
    proj_kernel<<<dim3(MB, 5), blk, 0, stream>>>(
        qry_bf, q_bf, wt_val, wt_off, wt_attn, b_val, b_off, b_attn,
        v_bf, cb, logits);
    deform_sample_kernel<<<(R_ROWS * NHEAD + 63) / 64, blk, 0, stream>>>(
        v_bf, cb, logits, vr, samp_bf);
    gemm_mfma_kernel<false, false><<<dim3(MB, 2), blk, 0, stream>>>(
        samp_bf, wt_out, b_out, cb, R_ROWS, 256, 256);
    add_ln_kernel<true><<<R_ROWS, blk, 0, stream>>>(query, cb, ln1g, ln1b, xb, samp_bf);
    gemm_mfma_kernel<true, true><<<dim3(MB, 8), blk, 0, stream>>>(
        samp_bf, wt_w1, b1, h_bf, R_ROWS, 1024, 256);
    gemm_mfma_kernel<false, false><<<dim3(MB, 2), blk, 0, stream>>>(
        h_bf, wt_w2, b2, cb, R_ROWS, 256, 1024);
    add_ln_kernel<false><<<R_ROWS, blk, 0, stream>>>(xb, cb, ln2g, ln2b, out, nullptr);
}

// Round 6
// 326.867 us; speedup vs baseline: 3.3468x; 1.0201x over previous
//
#include <hip/hip_runtime.h>
#include <math.h>

#define R_ROWS 26588
#define S_TOT  13294
#define NHEAD  8
#define NLVL   4
#define EPSF   1e-5f

typedef __attribute__((ext_vector_type(8))) short short8;
typedef __attribute__((ext_vector_type(4))) float f32x4;
typedef __attribute__((ext_vector_type(2))) float f32x2;
typedef unsigned short ushort_t;

__device__ __forceinline__ unsigned short f2bf(float f) {
    unsigned int u = __builtin_bit_cast(unsigned int, f);
    unsigned int r = (u + 0x7FFFu + ((u >> 16) & 1u)) >> 16;   // RNE
    return (unsigned short)r;
}

// ---------------------------------------------------------------------------
// All six weight transposes in ONE kernel. src f32 [K][N] -> dst bf16 [N][K].
// ---------------------------------------------------------------------------
__global__ __launch_bounds__(256) void transpose_all_kernel(
    const float* __restrict__ W_val, const float* __restrict__ W_off,
    const float* __restrict__ W_attn, const float* __restrict__ W_out,
    const float* __restrict__ W1, const float* __restrict__ W2,
    ushort_t* __restrict__ wt_val, ushort_t* __restrict__ wt_off,
    ushort_t* __restrict__ wt_attn, ushort_t* __restrict__ wt_out,
    ushort_t* __restrict__ wt_w1, ushort_t* __restrict__ wt_w2)
{
    int bid = blockIdx.x;
    const float* src; ushort_t* dst; int K, N, t;
    if (bid < 64)       { src = W_val;  dst = wt_val;  K = 256;  N = 256;  t = bid; }
    else if (bid < 128) { src = W_off;  dst = wt_off;  K = 256;  N = 256;  t = bid - 64; }
    else if (bid < 160) { src = W_attn; dst = wt_attn; K = 256;  N = 128;  t = bid - 128; }
    else if (bid < 224) { src = W_out;  dst = wt_out;  K = 256;  N = 256;  t = bid - 160; }
    else if (bid < 480) { src = W1;     dst = wt_w1;   K = 256;  N = 1024; t = bid - 224; }
    else                { src = W2;     dst = wt_w2;   K = 1024; N = 256;  t = bid - 480; }
    int nt = N / 32;
    int bn = (t % nt) * 32, bk = (t / nt) * 32;

    __shared__ ushort_t tt[32][33];
    int x = threadIdx.x & 31;
    int y = threadIdx.x >> 5;
#pragma unroll
    for (int i = 0; i < 4; ++i) {
        int k = y + i * 8;
        tt[x][k] = f2bf(src[(long)(bk + k) * N + bn + x]);
    }
    __syncthreads();
#pragma unroll
    for (int i = 0; i < 4; ++i) {
        int n = y + i * 8;
        dst[(long)(bn + n) * K + bk + x] = tt[n][x];
    }
}

// ---------------------------------------------------------------------------
// qry_bf = bf16(query), qsum_bf = bf16(query + qpos). 4 elem/thread.
// ---------------------------------------------------------------------------
__global__ __launch_bounds__(256) void addcvt_kernel(
    const float* __restrict__ q, const float* __restrict__ p,
    ushort_t* __restrict__ qry_bf, ushort_t* __restrict__ qsum_bf, int n4)
{
    int i = blockIdx.x * 256 + threadIdx.x;
    if (i >= n4) return;
    float4 a = ((const float4*)q)[i];
    float4 b = ((const float4*)p)[i];
    uint2 qa, qs;
    qa.x = (unsigned)f2bf(a.x) | ((unsigned)f2bf(a.y) << 16);
    qa.y = (unsigned)f2bf(a.z) | ((unsigned)f2bf(a.w) << 16);
    qs.x = (unsigned)f2bf(a.x + b.x) | ((unsigned)f2bf(a.y + b.y) << 16);
    qs.y = (unsigned)f2bf(a.z + b.z) | ((unsigned)f2bf(a.w + b.w) << 16);
    ((uint2*)qry_bf)[i] = qa;
    ((uint2*)qsum_bf)[i] = qs;
}

// ---------------------------------------------------------------------------
// Async triple-buffered GEMM: C[M,N] = A[M,K](bf16) @ Wt^T + bias.
// Block 256 = 4 waves (2x2); tile 128x128; wave 64x64; BK=32; 3 LDS buffers.
// Per iter: issue 4 DMA (tile t+1), s_waitcnt vmcnt(4) (tile t done, prefetch
// in flight), ONE raw s_barrier, compute tile t. WAR-safe: skew<=1 barrier,
// stage at iter t targets buf (t+1)%3, compute uses buf t%3.
// XOR quad swizzle on global side breaks LDS bank conflicts (2-way = free).
// ---------------------------------------------------------------------------
#define TBUF 4096   // 128*32 ushorts = 8 KB per buffer

__device__ __forceinline__ void stage_ab(
    const ushort_t* __restrict__ Arow, const ushort_t* __restrict__ Brow,
    int K, int k0, ushort_t* As, ushort_t* Bs, int wave, int lane)
{
    int quadS = lane & 3;
    int rr = lane >> 2;     // 0..15
#pragma unroll
    for (int inst = 0; inst < 2; ++inst) {
        int base_row = wave * 32 + inst * 16;
        int r = base_row + rr;
        int quadG = quadS ^ ((r >> 1) & 3);
        const ushort_t* gp = Arow + (long)r * K + k0 + quadG * 8;
        __builtin_amdgcn_global_load_lds(
            (const __attribute__((address_space(1))) unsigned int*)gp,
            (__attribute__((address_space(3))) unsigned int*)&As[base_row * 32],
            16, 0, 0);
    }
#pragma unroll
    for (int inst = 0; inst < 2; ++inst) {
        int base_row = wave * 32 + inst * 16;
        int r = base_row + rr;
        int quadG = quadS ^ ((r >> 1) & 3);
        const ushort_t* gp = Brow + (long)r * K + k0 + quadG * 8;
        __builtin_amdgcn_global_load_lds(
            (const __attribute__((address_space(1))) unsigned int*)gp,
            (__attribute__((address_space(3))) unsigned int*)&Bs[base_row * 32],
            16, 0, 0);
    }
}

__device__ __forceinline__ void gemm_body(
    ushort_t* As, ushort_t* Bs,   // flat [3*TBUF]
    const ushort_t* __restrict__ A, const ushort_t* __restrict__ Wt,
    const float* __restrict__ bias, void* __restrict__ Cv,
    int M, int N, int K, int bm, int bn, bool out_bf16, bool relu)
{
    const int tid  = threadIdx.x;
    const int wave = tid >> 6;
    const int lane = tid & 63;
    const int l15  = lane & 15;
    const int quad = lane >> 4;
    const int wm   = (wave >> 1) * 64;
    const int wn   = (wave & 1) * 64;

    const ushort_t* Arow = A + (long)bm * K;
    const ushort_t* Brow = Wt + (long)bn * K;

    f32x4 acc[4][4];
#pragma unroll
    for (int i = 0; i < 4; ++i)
#pragma unroll
        for (int j = 0; j < 4; ++j) acc[i][j] = (f32x4)0.0f;

    int aoff[4], boff[4];
#pragma unroll
    for (int mi = 0; mi < 4; ++mi) {
        int r = wm + mi * 16 + l15;
        aoff[mi] = r * 32 + (quad ^ ((r >> 1) & 3)) * 8;
    }
#pragma unroll
    for (int ni = 0; ni < 4; ++ni) {
        int r = wn + ni * 16 + l15;
        boff[ni] = r * 32 + (quad ^ ((r >> 1) & 3)) * 8;
    }

    const int NT = K >> 5;
    stage_ab(Arow, Brow, K, 0, As, Bs, wave, lane);
    int cur = 0;
    for (int t = 0; t < NT; ++t) {
        int nxt = cur + 1; if (nxt == 3) nxt = 0;
        if (t + 1 < NT) {
            stage_ab(Arow, Brow, K, (t + 1) << 5,
                     As + nxt * TBUF, Bs + nxt * TBUF, wave, lane);
            asm volatile("s_waitcnt vmcnt(4)" ::: "memory");
        } else {
            asm volatile("s_waitcnt vmcnt(0)" ::: "memory");
        }
        asm volatile("s_barrier" ::: "memory");

        const ushort_t* Ab = As + cur * TBUF;
        const ushort_t* Bb = Bs + cur * TBUF;
        short8 af[4], bf[4];
#pragma unroll
        for (int mi = 0; mi < 4; ++mi) af[mi] = *(const short8*)&Ab[aoff[mi]];
#pragma unroll
        for (int ni = 0; ni < 4; ++ni) bf[ni] = *(const short8*)&Bb[boff[ni]];
#pragma unroll
        for (int mi = 0; mi < 4; ++mi)
#pragma unroll
            for (int ni = 0; ni < 4; ++ni)
                acc[mi][ni] = __builtin_amdgcn_mfma_f32_16x16x32_bf16(
                    af[mi], bf[ni], acc[mi][ni], 0, 0, 0);
        cur = nxt;
    }

#pragma unroll
    for (int mi = 0; mi < 4; ++mi) {
#pragma unroll
        for (int r = 0; r < 4; ++r) {
            int row = bm + wm + mi * 16 + quad * 4 + r;
            if (row >= M) continue;
#pragma unroll
            for (int ni = 0; ni < 4; ++ni) {
                int col = bn + wn + ni * 16 + l15;
                float vv = acc[mi][ni][r] + bias[col];
                if (relu) vv = fmaxf(vv, 0.f);
                if (out_bf16)
                    ((ushort_t*)Cv)[(long)row * N + col] = f2bf(vv);
                else
                    ((float*)Cv)[(long)row * N + col] = vv;
            }
        }
    }
}

template<bool OUT_BF16, bool RELU>
__global__ __launch_bounds__(256) void gemm_mfma_kernel(
    const ushort_t* __restrict__ A, const ushort_t* __restrict__ Wt,
    const float* __restrict__ bias, void* __restrict__ Cv,
    int M, int N, int K)
{
    __shared__ ushort_t As[3 * TBUF];
    __shared__ ushort_t Bs[3 * TBUF];
    gemm_body(As, Bs, A, Wt, bias, Cv, M, N, K,
              blockIdx.x * 128, blockIdx.y * 128, OUT_BF16, RELU);
}

// Combined val/off/attn projections. grid = (MB, 5).
__global__ __launch_bounds__(256) void proj_kernel(
    const ushort_t* __restrict__ qry_bf, const ushort_t* __restrict__ q_bf,
    const ushort_t* __restrict__ wt_val, const ushort_t* __restrict__ wt_off,
    const ushort_t* __restrict__ wt_attn,
    const float* __restrict__ b_val, const float* __restrict__ b_off,
    const float* __restrict__ b_attn,
    ushort_t* __restrict__ v_bf, float* __restrict__ cb, float* __restrict__ logits)
{
    __shared__ ushort_t As[3 * TBUF];
    __shared__ ushort_t Bs[3 * TBUF];
    int y = blockIdx.y;
    const ushort_t* A; const ushort_t* Wt; const float* bias;
    void* C; bool outbf; int N, bn;
    if (y < 2)      { A = qry_bf; Wt = wt_val;  bias = b_val;  C = v_bf;   outbf = true;  N = 256; bn = y * 128; }
    else if (y < 4) { A = q_bf;   Wt = wt_off;  bias = b_off;  C = cb;     outbf = false; N = 256; bn = (y - 2) * 128; }
    else            { A = q_bf;   Wt = wt_attn; bias = b_attn; C = logits; outbf = false; N = 128; bn = 0; }
    gemm_body(As, Bs, A, Wt, bias, C, R_ROWS, N, 256, blockIdx.x * 128, bn, outbf, false);
}

// ---------------------------------------------------------------------------
// Deformable sampling + fused softmax, lane-specialized, XCD-swizzled.
// grid = 3328 blocks (8 XCDs x 416); XCD x gets a CONTIGUOUS query range so
// its L2 sees ~1/8 of v instead of all of it.
// ---------------------------------------------------------------------------
#define DEF_BLOCKS 3328
#define DEF_CHUNK  416   // DEF_BLOCKS / 8

__global__ __launch_bounds__(256) void deform_sample_kernel(
    const ushort_t* __restrict__ v, const float* __restrict__ off,
    const float* __restrict__ logits, const float* __restrict__ vr,
    ushort_t* __restrict__ out)
{
    const int Hs_[4] = {100, 50, 25, 13};
    const int S0_[4] = {0, 10000, 12500, 13125};

    int wb  = (blockIdx.x & 7) * DEF_CHUNK + (blockIdx.x >> 3);  // XCD-contiguous
    int grp = wb * 64 + (threadIdx.x >> 2);
    int j   = threadIdx.x & 3;
    if (grp >= R_ROWS * NHEAD) return;
    int h = grp & 7;
    int r = grp >> 3;
    int b = (r >= S_TOT) ? 1 : 0;
    int s = r - b * S_TOT;

    int lq = (s < 10000) ? 0 : (s < 12500) ? 1 : (s < 13125) ? 2 : 3;
    int t  = s - S0_[lq];
    int Wq = Hs_[lq];
    int iy = t / Wq;
    int jx = t - iy * Wq;
    float vx = vr[(b * NLVL + lq) * 2 + 0];
    float vy = vr[(b * NLVL + lq) * 2 + 1];
    float rx = (jx + 0.5f) / (vx * (float)Wq);
    float ry = (iy + 0.5f) / (vy * (float)Wq);

    const float* offp = off + (long)r * 256 + h * 32;
    float4 oa = ((const float4*)offp)[2 * j];
    float4 ob = ((const float4*)offp)[2 * j + 1];
    float4 lg = ((const float4*)(logits + (long)grp * 16))[j];

    float mx = fmaxf(fmaxf(lg.x, lg.y), fmaxf(lg.z, lg.w));
    mx = fmaxf(mx, __shfl_xor(mx, 1));
    mx = fmaxf(mx, __shfl_xor(mx, 2));
    float e0 = __expf(lg.x - mx), e1 = __expf(lg.y - mx);
    float e2 = __expf(lg.z - mx), e3 = __expf(lg.w - mx);
    float sum = e0 + e1 + e2 + e3;
    sum += __shfl_xor(sum, 1);
    sum += __shfl_xor(sum, 2);
    float inv = 1.f / sum;

    const int   H  = Hs_[j];
    const float fH = (float)H;
    const int   s0 = S0_[j];
    float oxs[4] = {oa.x, oa.z, ob.x, ob.z};
    float oys[4] = {oa.y, oa.w, ob.y, ob.w};
    float wts[4] = {e0 * inv, e1 * inv, e2 * inv, e3 * inv};
    float pw0[4], pw1[4], pw2[4], pw3[4];
    int   pi0[4], pi1[4], pi2[4], pi3[4];
#pragma unroll
    for (int i = 0; i < 4; ++i) {
        float x = rx * fH + oxs[i] - 0.5f;
        float y = ry * fH + oys[i] - 0.5f;
        float xf = floorf(x), yf = floorf(y);
        float lx = x - xf, ly = y - yf;
        int x0 = (int)xf, y0 = (int)yf;
        bool xv0 = (x0 >= 0) & (x0 < H);
        bool xv1 = (x0 >= -1) & (x0 < H - 1);
        bool yv0 = (y0 >= 0) & (y0 < H);
        bool yv1 = (y0 >= -1) & (y0 < H - 1);
        float w = wts[i];
        pw0[i] = (xv0 & yv0) ? (1.f - lx) * (1.f - ly) * w : 0.f;
        pw1[i] = (xv1 & yv0) ? lx * (1.f - ly) * w : 0.f;
        pw2[i] = (xv0 & yv1) ? (1.f - lx) * ly * w : 0.f;
        pw3[i] = (xv1 & yv1) ? lx * ly * w : 0.f;
        int xc0 = min(max(x0, 0), H - 1), xc1 = min(max(x0 + 1, 0), H - 1);
        int yc0 = min(max(y0, 0), H - 1), yc1 = min(max(y0 + 1, 0), H - 1);
        pi0[i] = s0 + yc0 * H + xc0;
        pi1[i] = s0 + yc0 * H + xc1;
        pi2[i] = s0 + yc1 * H + xc0;
        pi3[i] = s0 + yc1 * H + xc1;
    }

    const ushort_t* vb = v + ((long)b * S_TOT) * 256 + h * 32 + j * 8;
    f32x2 acc2[4];
#pragma unroll
    for (int c = 0; c < 4; ++c) acc2[c] = (f32x2)0.0f;

#define ACC_CORNER(IDX, WGT) do {                                            \
        uint4 g = *(const uint4*)&vb[(long)(IDX) * 256];                     \
        unsigned uu0 = g.x, uu1 = g.y, uu2 = g.z, uu3 = g.w;                 \
        f32x2 gv;                                                            \
        gv.x = __builtin_bit_cast(float, uu0 << 16);                         \
        gv.y = __builtin_bit_cast(float, uu0 & 0xFFFF0000u);                 \
        acc2[0] += gv * (WGT);                                               \
        gv.x = __builtin_bit_cast(float, uu1 << 16);                         \
        gv.y = __builtin_bit_cast(float, uu1 & 0xFFFF0000u);                 \
        acc2[1] += gv * (WGT);                                               \
        gv.x = __builtin_bit_cast(float, uu2 << 16);                         \
        gv.y = __builtin_bit_cast(float, uu2 & 0xFFFF0000u);                 \
        acc2[2] += gv * (WGT);                                               \
        gv.x = __builtin_bit_cast(float, uu3 << 16);                         \
        gv.y = __builtin_bit_cast(float, uu3 & 0xFFFF0000u);                 \
        acc2[3] += gv * (WGT);                                               \
    } while (0)

#pragma unroll
    for (int i = 0; i < 4; ++i) {
#pragma unroll
        for (int j2 = 0; j2 < 4; ++j2) {
            float w00 = __shfl(pw0[i], j2, 4);
            float w01 = __shfl(pw1[i], j2, 4);
            float w10 = __shfl(pw2[i], j2, 4);
            float w11 = __shfl(pw3[i], j2, 4);
            int   i00 = __shfl(pi0[i], j2, 4);
            int   i01 = __shfl(pi1[i], j2, 4);
            int   i10 = __shfl(pi2[i], j2, 4);
            int   i11 = __shfl(pi3[i], j2, 4);
            ACC_CORNER(i00, w00);
            ACC_CORNER(i01, w01);
            ACC_CORNER(i10, w10);
            ACC_CORNER(i11, w11);
        }
    }
#undef ACC_CORNER

    uint4 o;
    o.x = (unsigned)f2bf(acc2[0].x) | ((unsigned)f2bf(acc2[0].y) << 16);
    o.y = (unsigned)f2bf(acc2[1].x) | ((unsigned)f2bf(acc2[1].y) << 16);
    o.z = (unsigned)f2bf(acc2[2].x) | ((unsigned)f2bf(acc2[2].y) << 16);
    o.w = (unsigned)f2bf(acc2[3].x) | ((unsigned)f2bf(acc2[3].y) << 16);
    *(uint4*)&out[(long)r * 256 + h * 32 + j * 8] = o;
}

// ---------------------------------------------------------------------------
// out = LayerNorm(a + b); optionally also emit bf16 copy
// ---------------------------------------------------------------------------
template<bool DUAL>
__global__ __launch_bounds__(256) void add_ln_kernel(
    const float* __restrict__ a, const float* __restrict__ b,
    const float* __restrict__ g, const float* __restrict__ beta,
    float* __restrict__ outf, ushort_t* __restrict__ outb)
{
    int row = blockIdx.x;
    int tid = threadIdx.x;
    float x = a[(long)row * 256 + tid] + b[(long)row * 256 + tid];
    float s1 = x, s2 = x * x;
#pragma unroll
    for (int o = 32; o > 0; o >>= 1) {
        s1 += __shfl_down(s1, o, 64);
        s2 += __shfl_down(s2, o, 64);
    }
    __shared__ float sh1[4], sh2[4];
    int w = tid >> 6;
    if ((tid & 63) == 0) { sh1[w] = s1; sh2[w] = s2; }
    __syncthreads();
    float t1 = sh1[0] + sh1[1] + sh1[2] + sh1[3];
    float t2 = sh2[0] + sh2[1] + sh2[2] + sh2[3];
    float mean = t1 * (1.f / 256.f);
    float var  = t2 * (1.f / 256.f) - mean * mean;
    float inv  = rsqrtf(var + EPSF);
    float y = (x - mean) * inv * g[tid] + beta[tid];
    outf[(long)row * 256 + tid] = y;
    if (DUAL) outb[(long)row * 256 + tid] = f2bf(y);
}

// ---------------------------------------------------------------------------
extern "C" void kernel_launch(void* const* d_in, const int* in_sizes, int n_in,
                              void* d_out, int out_size, void* d_ws, size_t ws_size,
                              hipStream_t stream)
{
    const float* query  = (const float*)d_in[0];
    const float* qpos   = (const float*)d_in[1];
    const float* vr     = (const float*)d_in[2];
    const float* W_off  = (const float*)d_in[5];
    const float* b_off  = (const float*)d_in[6];
    const float* W_attn = (const float*)d_in[7];
    const float* b_attn = (const float*)d_in[8];
    const float* W_val  = (const float*)d_in[9];
    const float* b_val  = (const float*)d_in[10];
    const float* W_out  = (const float*)d_in[11];
    const float* b_out  = (const float*)d_in[12];
    const float* ln1g   = (const float*)d_in[13];
    const float* ln1b   = (const float*)d_in[14];
    const float* W1     = (const float*)d_in[15];
    const float* b1     = (const float*)d_in[16];
    const float* W2     = (const float*)d_in[17];
    const float* b2     = (const float*)d_in[18];
    const float* ln2g   = (const float*)d_in[19];
    const float* ln2b   = (const float*)d_in[20];
    float* out = (float*)d_out;

    float* ws = (float*)d_ws;
    const long R128 = (long)R_ROWS * 128;
    ushort_t* q_bf    = (ushort_t*)(ws);                 // R x 256 bf16
    ushort_t* qry_bf  = (ushort_t*)(ws + R128);          // R x 256 bf16
    ushort_t* v_bf    = (ushort_t*)(ws + 2 * R128);      // R x 256 bf16
    float*    logits  = ws + 3 * R128;                   // R x 128 f32
    ushort_t* h_bf    = (ushort_t*)(ws);                 // R x 1024 bf16 (overlays the 4 above)
    float*    cb      = ws + 4 * R128;                   // R x 256 f32: off -> attn_out -> f
    ushort_t* samp_bf = (ushort_t*)(ws + 6 * R128);      // R x 256 bf16: sampled -> x_bf
    float*    xb      = ws + 7 * R128;                   // R x 256 f32: x (LN1 out)
    ushort_t* wt      = (ushort_t*)(ws + 9 * R128);
    ushort_t* wt_val  = wt;                 // 256x256
    ushort_t* wt_off  = wt + 65536;         // 256x256
    ushort_t* wt_attn = wt + 131072;        // 128x256
    ushort_t* wt_out  = wt + 163840;        // 256x256
    ushort_t* wt_w1   = wt + 229376;        // 1024x256
    ushort_t* wt_w2   = wt + 491520;        // 256x1024

    dim3 blk(256);
    const int MB = (R_ROWS + 127) / 128;   // 208

    transpose_all_kernel<<<736, blk, 0, stream>>>(
        W_val, W_off, W_attn, W_out, W1, W2,
        wt_val, wt_off, wt_attn, wt_out, wt_w1, wt_w2);
    addcvt_kernel<<<(R_ROWS * 64 + 255) / 256, blk, 0, stream>>>(
        query, qpos, qry_bf, q_bf, R_ROWS * 64);
    proj_kernel<<<dim3(MB, 5), blk, 0, stream>>>(
        qry_bf, q_bf, wt_val, wt_off, wt_attn, b_val, b_off, b_attn,
        v_bf, cb, logits);
    deform_sample_kernel<<<DEF_BLOCKS, blk, 0, stream>>>(
        v_bf, cb, logits, vr, samp_bf);
    gemm_mfma_kernel<false, false><<<dim3(MB, 2), blk, 0, stream>>>(
        samp_bf, wt_out, b_out, cb, R_ROWS, 256, 256);
    add_ln_kernel<true><<<R_ROWS, blk, 0, stream>>>(query, cb, ln1g, ln1b, xb, samp_bf);
    gemm_mfma_kernel<true, true><<<dim3(MB, 8), blk, 0, stream>>>(
        samp_bf, wt_w1, b1, h_bf, R_ROWS, 1024, 256);
    gemm_mfma_kernel<false, false><<<dim3(MB, 2), blk, 0, stream>>>(
        h_bf, wt_w2, b2, cb, R_ROWS, 256, 1024);
    add_ln_kernel<false><<<R_ROWS, blk, 0, stream>>>(xb, cb, ln2g, ln2b, out, nullptr);
}